// Round 5
// baseline (319.363 us; speedup 1.0000x reference)
//
#include <hip/hip_runtime.h>
#include <math.h>

#define NN 1536
#define FF 32
#define HH 64
#define EE (NN*(NN-1)/2)   // 1178880 = 73680 * 16
#define NGRP (EE/16)       // 73680 groups of 16 edges
#define GPW 8              // groups per wave; 2304 blocks * 4 waves * 8 = 73728
#define EBLK 2304
#define BN_EPS 1e-5f
#define SLOPE 0.01f

typedef _Float16 v8h  __attribute__((ext_vector_type(8)));
typedef float    f32x4 __attribute__((ext_vector_type(4)));
typedef float    f32x8 __attribute__((ext_vector_type(8)));

union V8H { v8h v; float4 f4; };

__device__ __forceinline__ float lrelu_f(float v){ return v >= 0.f ? v : SLOPE*v; }

// ---------------------------------------------------------------------------
// Fused GIN layer: block b owns rows [16b,16b+16).
//  phase1: h = (FIRST ? zin : lrelu(BN(zin))); u = (1+eps)h + exclusive prefix
//  phase2: z = relu(relu(u@W1+b1)@W2+b2)  -> zout
//  phase3: per-block BN partial sums; last block reduces -> stats_out, resets counter
// FIRST instantiation is launched with 128 blocks; blocks >=96 run the edge-MLP
// weight fragment prep (W2^T/W3^T -> f16 MFMA A-fragments).
template<int DIN, bool FIRST>
__global__ __launch_bounds__(256) void k_gin(
    const float* __restrict__ zin, const float* __restrict__ stats_in,
    const float* __restrict__ gg, const float* __restrict__ be,
    const float* __restrict__ eps_p,
    const float* __restrict__ W1, const float* __restrict__ b1,
    const float* __restrict__ W2, const float* __restrict__ b2,
    float* __restrict__ zout,
    float* __restrict__ partial, int* __restrict__ counter,
    float* __restrict__ stats_out,
    const float* __restrict__ pw2, const float* __restrict__ pw3,
    _Float16* __restrict__ pwf) {
  int bid = blockIdx.x;
  if (FIRST && bid >= 96) {
    // ---- edge-weight fragment prep (8192 elements over 32 blocks) ----
    int i = (bid - 96)*256 + threadIdx.x;
    int mat = i >> 12, r = i & 4095;
    int k = r >> 6, cout = r & 63;
    int m = cout >> 4, cc = cout & 15;
    int q, g, b;
    if (mat == 0) { q = k >> 5; g = (k >> 3) & 3; b = k & 7; }
    else { int mF = k >> 4; g = (k >> 2) & 3; int rr = k & 3; q = mF >> 1; b = ((mF & 1) << 2) | rr; }
    const float* W = mat ? pw3 : pw2;
    pwf[mat*4096 + ((q*4 + m)*64 + (g*16 + cc))*8 + b] = (_Float16)W[r];
    return;
  }

  __shared__ float W1s[DIN*64];
  __shared__ float W2s[64*64];
  __shared__ float uls[16][DIN];
  __shared__ float t1s[16][64];
  __shared__ float part4[4][64];
  __shared__ float part4q[4][64];
  __shared__ float sums[128];
  __shared__ int lastf;

  int tid = threadIdx.x, c = tid & 63, y = tid >> 6;
  for (int i = tid; i < DIN*64; i += 256) W1s[i] = W1[i];
  for (int i = tid; i < 4096; i += 256)   W2s[i] = W2[i];

  int r0 = bid*16;
  float mean = 0.f, inv = 0.f, ga = 0.f, bb = 0.f;
  if (!FIRST) { mean = stats_in[c]; inv = rsqrtf(stats_in[64 + c] + BN_EPS); ga = gg[c]; bb = be[c]; }

  // phase 1: partial prefix over rows < r0 (strided by y)
  float s = 0.f;
  if (c < DIN) {
    for (int n = y; n < r0; n += 4) {
      float v = zin[n*DIN + c];
      if (!FIRST) v = lrelu_f((v - mean)*inv*ga + bb);
      s += v;
    }
  }
  part4[y][c] = s;
  __syncthreads();
  if (y == 0 && c < DIN) {
    float run = part4[0][c] + part4[1][c] + part4[2][c] + part4[3][c];
    float e1 = 1.f + eps_p[0];
    for (int n = r0; n < r0 + 16; ++n) {
      float v = zin[n*DIN + c];
      if (!FIRST) v = lrelu_f((v - mean)*inv*ga + bb);
      uls[n - r0][c] = e1*v + run;
      run += v;
    }
  }
  __syncthreads();

  // phase 2a: t1 = relu(u @ W1 + b1), rows y,y+4,y+8,y+12
  float a0 = b1[c], a1 = a0, a2 = a0, a3 = a0;
  for (int k = 0; k < DIN; ++k) {
    float w = W1s[k*64 + c];
    a0 = fmaf(uls[y][k],      w, a0);
    a1 = fmaf(uls[y + 4][k],  w, a1);
    a2 = fmaf(uls[y + 8][k],  w, a2);
    a3 = fmaf(uls[y + 12][k], w, a3);
  }
  t1s[y][c]      = fmaxf(a0, 0.f);
  t1s[y + 4][c]  = fmaxf(a1, 0.f);
  t1s[y + 8][c]  = fmaxf(a2, 0.f);
  t1s[y + 12][c] = fmaxf(a3, 0.f);
  __syncthreads();

  // phase 2b: z = relu(t1 @ W2 + b2)
  float z0 = b2[c], z1 = z0, z2 = z0, z3 = z0;
  for (int k = 0; k < 64; ++k) {
    float w = W2s[k*64 + c];
    z0 = fmaf(t1s[y][k],      w, z0);
    z1 = fmaf(t1s[y + 4][k],  w, z1);
    z2 = fmaf(t1s[y + 8][k],  w, z2);
    z3 = fmaf(t1s[y + 12][k], w, z3);
  }
  z0 = fmaxf(z0, 0.f); z1 = fmaxf(z1, 0.f); z2 = fmaxf(z2, 0.f); z3 = fmaxf(z3, 0.f);
  zout[(r0 + y)*64 + c]      = z0;
  zout[(r0 + y + 4)*64 + c]  = z1;
  zout[(r0 + y + 8)*64 + c]  = z2;
  zout[(r0 + y + 12)*64 + c] = z3;

  // phase 3: BN partials + last-block reduce
  part4[y][c]  = z0 + z1 + z2 + z3;
  part4q[y][c] = z0*z0 + z1*z1 + z2*z2 + z3*z3;
  __syncthreads();
  if (y == 0) {
    partial[bid*128 + c]      = part4[0][c] + part4[1][c] + part4[2][c] + part4[3][c];
    partial[bid*128 + 64 + c] = part4q[0][c] + part4q[1][c] + part4q[2][c] + part4q[3][c];
  }
  __threadfence();
  __syncthreads();
  if (tid == 0) { int old = atomicAdd(counter, 1); lastf = (old == 95); }
  __syncthreads();
  if (lastf) {
    __threadfence();
    if (tid < 128) {
      float S = 0.f;
      for (int b = 0; b < 96; ++b) S += partial[b*128 + tid];
      sums[tid] = S;
    }
    __syncthreads();
    if (tid < 64) {
      float m = sums[tid] / NN;
      stats_out[tid]      = m;
      stats_out[64 + tid] = sums[64 + tid] / NN - m*m;
    }
    if (tid == 0) *counter = 0;
  }
}

// ---------------------------------------------------------------------------
// head: h3=lrelu(BN(z)); hf=lrelu(lrelu(h3@lin1)@lin2)+nf; A=hf@W1a+b1e; B=hf@W1b
__global__ __launch_bounds__(256) void k_head(
    const float* __restrict__ z, const float* __restrict__ stats,
    const float* __restrict__ gg, const float* __restrict__ be,
    const float* __restrict__ l1w, const float* __restrict__ l1b,
    const float* __restrict__ l2w, const float* __restrict__ l2b,
    const float* __restrict__ nf,
    const float* __restrict__ epw1, const float* __restrict__ epb1,
    _Float16* __restrict__ Ah, _Float16* __restrict__ Bh) {
  __shared__ float W1s[4096];
  __shared__ float W2s[2048];
  __shared__ float Was[2048];
  __shared__ float Wbs[2048];
  __shared__ float t0[16][64], t1[16][64], t2[16][32];
  int tid = threadIdx.x, c = tid & 63, y = tid >> 6;
  for (int i = tid; i < 4096; i += 256) W1s[i] = l1w[i];
  for (int i = tid; i < 2048; i += 256) { W2s[i] = l2w[i]; Was[i] = epw1[i]; Wbs[i] = epw1[2048 + i]; }
  int r0 = blockIdx.x*16;
  float mean = stats[c], inv = rsqrtf(stats[64 + c] + BN_EPS), ga = gg[c], bb = be[c];
#pragma unroll
  for (int i = 0; i < 4; ++i) {
    int r = y + 4*i;
    t0[r][c] = lrelu_f((z[(r0 + r)*64 + c] - mean)*inv*ga + bb);
  }
  __syncthreads();
  {
    float a0 = l1b[c], a1 = a0, a2 = a0, a3 = a0;
    for (int k = 0; k < 64; ++k) {
      float w = W1s[k*64 + c];
      a0 = fmaf(t0[y][k],      w, a0);
      a1 = fmaf(t0[y + 4][k],  w, a1);
      a2 = fmaf(t0[y + 8][k],  w, a2);
      a3 = fmaf(t0[y + 12][k], w, a3);
    }
    t1[y][c] = lrelu_f(a0); t1[y + 4][c] = lrelu_f(a1);
    t1[y + 8][c] = lrelu_f(a2); t1[y + 12][c] = lrelu_f(a3);
  }
  __syncthreads();
  if (c < 32) {
    float v0 = l2b[c], v1 = v0, v2 = v0, v3 = v0;
    for (int k = 0; k < 64; ++k) {
      float w = W2s[k*32 + c];
      v0 = fmaf(t1[y][k],      w, v0);
      v1 = fmaf(t1[y + 4][k],  w, v1);
      v2 = fmaf(t1[y + 8][k],  w, v2);
      v3 = fmaf(t1[y + 12][k], w, v3);
    }
    t2[y][c]      = lrelu_f(v0) + nf[(r0 + y)*32 + c];
    t2[y + 4][c]  = lrelu_f(v1) + nf[(r0 + y + 4)*32 + c];
    t2[y + 8][c]  = lrelu_f(v2) + nf[(r0 + y + 8)*32 + c];
    t2[y + 12][c] = lrelu_f(v3) + nf[(r0 + y + 12)*32 + c];
  }
  __syncthreads();
  {
    float av0 = epb1[c], av1 = av0, av2 = av0, av3 = av0;
    float bv0 = 0.f, bv1 = 0.f, bv2 = 0.f, bv3 = 0.f;
    for (int k = 0; k < 32; ++k) {
      float wa = Was[k*64 + c], wb = Wbs[k*64 + c];
      av0 = fmaf(t2[y][k], wa, av0);      bv0 = fmaf(t2[y][k], wb, bv0);
      av1 = fmaf(t2[y + 4][k], wa, av1);  bv1 = fmaf(t2[y + 4][k], wb, bv1);
      av2 = fmaf(t2[y + 8][k], wa, av2);  bv2 = fmaf(t2[y + 8][k], wb, bv2);
      av3 = fmaf(t2[y + 12][k], wa, av3); bv3 = fmaf(t2[y + 12][k], wb, bv3);
    }
    Ah[(r0 + y)*64 + c]      = (_Float16)av0;  Bh[(r0 + y)*64 + c]      = (_Float16)bv0;
    Ah[(r0 + y + 4)*64 + c]  = (_Float16)av1;  Bh[(r0 + y + 4)*64 + c]  = (_Float16)bv1;
    Ah[(r0 + y + 8)*64 + c]  = (_Float16)av2;  Bh[(r0 + y + 8)*64 + c]  = (_Float16)bv2;
    Ah[(r0 + y + 12)*64 + c] = (_Float16)av3;  Bh[(r0 + y + 12)*64 + c] = (_Float16)bv3;
  }
}

// ---------------------------------------------------------------------------
__device__ __forceinline__ int ebase(int s) { return s*(2*NN - 1 - s)/2; }

// edge MLP, swapped-operand MFMA. Lane (c,g): edge=c preserved across layers.
// launch_bounds(256,2): VGPR cap 256 keeps weights+biases resident (84-VGPR
// heuristic at default caused per-iteration bias refetch = round-4 stall).
__global__ __launch_bounds__(256, 2) void k_edges_f16(
    const _Float16* __restrict__ Ah, const _Float16* __restrict__ Bh,
    const _Float16* __restrict__ Wf,
    const float* __restrict__ b2, const float* __restrict__ b3,
    const float* __restrict__ w4, const float* __restrict__ b4,
    float* __restrict__ out) {
  int tid = threadIdx.x, wid = tid >> 6, lane = tid & 63;
  int c = lane & 15, g = lane >> 4;

  const v8h* wp = (const v8h*)Wf;
  v8h wv2[8], wv3[8];
#pragma unroll
  for (int f = 0; f < 8; ++f) { wv2[f] = wp[f*64 + lane]; wv3[f] = wp[512 + f*64 + lane]; }

  // biases pre-shaped as MFMA C-operands: b2v[m][r] = bias of feature 16m+4g+r
  f32x4 b2v[4], b3v[4], w4v[4];
  int g4 = g*4;
#pragma unroll
  for (int m = 0; m < 4; ++m)
#pragma unroll
    for (int r = 0; r < 4; ++r) {
      int f = 16*m + g4 + r;
      b2v[m][r] = b2[f]; b3v[m][r] = b3[f]; w4v[m][r] = w4[f];
    }
  float b4v = b4[0];

  V8H zu; zu.f4 = make_float4(0.f, 0.f, 0.f, 0.f);
  const v8h vzero = zu.v;

  int grp = (blockIdx.x*4 + wid)*GPW;
  if (grp >= NGRP) return;

  // initial decode of edge e = grp*16 + c -> (s,t)
  int e = grp*16 + c;
  float disc = (float)((2*NN-1)*(2*NN-1) - 8*e);
  int s = (int)((2.f*NN - 1.f - sqrtf(disc)) * 0.5f);
  if (s < 0) s = 0;
  if (s > NN-2) s = NN-2;
  while (s > 0 && e < ebase(s)) --s;
  while (e >= ebase(s+1)) ++s;
  int t = s + 1 + (e - ebase(s));

  // preload first group's activations
  V8H x0, x1, y0v, y1v;
  x0.f4  = *(const float4*)(Ah + s*64 + g*8);
  x1.f4  = *(const float4*)(Ah + s*64 + 32 + g*8);
  y0v.f4 = *(const float4*)(Bh + t*64 + g*8);
  y1v.f4 = *(const float4*)(Bh + t*64 + 32 + g*8);

  for (int it = 0; it < GPW; ++it, ++grp) {
    if (grp >= NGRP) break;
    int cs = s, ct = t;

    // consume prefetched activations -> L1 fragments
    V8H f0, f1;
    f0.v = __builtin_elementwise_max(x0.v + y0v.v, vzero);
    f1.v = __builtin_elementwise_max(x1.v + y1v.v, vzero);

    // advance + prefetch next group (last prefetch lands in safe ws region)
    t += 16;
    while (t >= NN && s < NN-1) { int o = t - NN; ++s; t = s + 1 + o; }
    x0.f4  = *(const float4*)(Ah + s*64 + g*8);
    x1.f4  = *(const float4*)(Ah + s*64 + 32 + g*8);
    y0v.f4 = *(const float4*)(Bh + t*64 + g*8);
    y1v.f4 = *(const float4*)(Bh + t*64 + 32 + g*8);

    // layer 2 (bias as C-operand)
    f32x4 acc[4];
#pragma unroll
    for (int m = 0; m < 4; ++m)
      acc[m] = __builtin_amdgcn_mfma_f32_16x16x32_f16(wv2[m],     f0.v, b2v[m], 0, 0, 0);
#pragma unroll
    for (int m = 0; m < 4; ++m)
      acc[m] = __builtin_amdgcn_mfma_f32_16x16x32_f16(wv2[4 + m], f1.v, acc[m], 0, 0, 0);

    // relu + pack to f16 (D-layout feeds layer-3 B-frags directly)
    f32x8 q0, q1;
#pragma unroll
    for (int r = 0; r < 4; ++r) {
      q0[r]     = fmaxf(acc[0][r], 0.f);
      q0[4 + r] = fmaxf(acc[1][r], 0.f);
      q1[r]     = fmaxf(acc[2][r], 0.f);
      q1[4 + r] = fmaxf(acc[3][r], 0.f);
    }
    v8h p0 = __builtin_convertvector(q0, v8h);
    v8h p1 = __builtin_convertvector(q1, v8h);

    // layer 3
    f32x4 acc3[4];
#pragma unroll
    for (int m = 0; m < 4; ++m)
      acc3[m] = __builtin_amdgcn_mfma_f32_16x16x32_f16(wv3[m],     p0, b3v[m], 0, 0, 0);
#pragma unroll
    for (int m = 0; m < 4; ++m)
      acc3[m] = __builtin_amdgcn_mfma_f32_16x16x32_f16(wv3[4 + m], p1, acc3[m], 0, 0, 0);

    // layer 4 + reduce over g
    float p = 0.f;
#pragma unroll
    for (int m = 0; m < 4; ++m)
#pragma unroll
      for (int r = 0; r < 4; ++r)
        p = fmaf(fmaxf(acc3[m][r], 0.f), w4v[m][r], p);
    p += __shfl_xor(p, 16, 64);
    p += __shfl_xor(p, 32, 64);
    float ez = __builtin_amdgcn_exp2f(-1.44269504f * (p + b4v));
    float prob = __builtin_amdgcn_rcpf(1.f + ez);
    if (lane < 16) out[cs*NN + ct] = prob;   // upper triangle, coalesced
  }
}

// mirror: lower = upper^T, diag = 0. Triangular grid (bi >= bj).
__global__ __launch_bounds__(256) void k_mirror(float* __restrict__ out) {
  __shared__ float tile[32][33];
  int k = blockIdx.x;
  int bi = (int)((sqrtf(8.f*k + 1.f) - 1.f)*0.5f);
  while (bi*(bi + 1)/2 > k) --bi;
  while ((bi + 1)*(bi + 2)/2 <= k) ++bi;
  int bj = k - bi*(bi + 1)/2;
  int i0 = bi*32, j0 = bj*32;
  int tx = threadIdx.x & 31, ty = threadIdx.x >> 5;   // 32 x 8
#pragma unroll
  for (int r = 0; r < 4; ++r)
    tile[ty + r*8][tx] = out[(j0 + ty + r*8)*NN + i0 + tx];
  __syncthreads();
#pragma unroll
  for (int r = 0; r < 4; ++r) {
    int row = ty + r*8;
    int i = i0 + row, j = j0 + tx;
    if (bi > bj)      out[i*NN + j] = tile[tx][row];
    else if (i > j)   out[i*NN + j] = tile[tx][row];
    else if (i == j)  out[i*NN + j] = 0.f;
  }
}

// ---------------------------------------------------------------------------
extern "C" void kernel_launch(void* const* d_in, const int* in_sizes, int n_in,
                              void* d_out, int out_size, void* d_ws, size_t ws_size,
                              hipStream_t stream) {
  const float* nf     = (const float*)d_in[1];
  const float* c1_eps = (const float*)d_in[2];
  const float* c1_w1  = (const float*)d_in[3];
  const float* c1_b1  = (const float*)d_in[4];
  const float* c1_w2  = (const float*)d_in[5];
  const float* c1_b2  = (const float*)d_in[6];
  const float* c1_g   = (const float*)d_in[7];
  const float* c1_be  = (const float*)d_in[8];
  const float* cv_eps = (const float*)d_in[9];
  const float* cv_w1  = (const float*)d_in[10];
  const float* cv_b1  = (const float*)d_in[11];
  const float* cv_w2  = (const float*)d_in[12];
  const float* cv_b2  = (const float*)d_in[13];
  const float* cv_g   = (const float*)d_in[14];
  const float* cv_be  = (const float*)d_in[15];
  const float* lin1_w = (const float*)d_in[16];
  const float* lin1_b = (const float*)d_in[17];
  const float* lin2_w = (const float*)d_in[18];
  const float* lin2_b = (const float*)d_in[19];
  const float* ep_w1  = (const float*)d_in[20];
  const float* ep_b1  = (const float*)d_in[21];
  const float* ep_w2  = (const float*)d_in[22];
  const float* ep_b2  = (const float*)d_in[23];
  const float* ep_w3  = (const float*)d_in[24];
  const float* ep_b3  = (const float*)d_in[25];
  const float* ep_w4  = (const float*)d_in[26];
  const float* ep_b4  = (const float*)d_in[27];

  float* ws = (float*)d_ws;
  float* zA     = ws;                     // [NN*64]
  float* zB     = zA + NN*64;             // [NN*64]
  float* statsA = zB + NN*64;             // [128]
  float* statsB = statsA + 128;
  float* statsC = statsB + 128;
  _Float16* Ah  = (_Float16*)(statsC + 128);  // [NN*64] f16
  _Float16* Bh  = Ah + NN*64;                 // [NN*64] f16
  _Float16* Wf  = Bh + NN*64;                 // [2*4096] f16 (absorbs Bh prefetch overread)
  float* partial = (float*)(Wf + 8192);       // [96*128]
  int* counter   = (int*)(partial + 96*128);

  float* out = (float*)d_out;

  hipMemsetAsync(counter, 0, sizeof(int), stream);

  // GIN layer 1 (F=32 -> H=64) + edge-weight prep in blocks 96..127
  k_gin<32, true><<<128, 256, 0, stream>>>(nf, nullptr, nullptr, nullptr, c1_eps,
      c1_w1, c1_b1, c1_w2, c1_b2, zA, partial, counter, statsA, ep_w2, ep_w3, Wf);

  // GIN layer 2: read zA (BN via statsA + c1_g/be), write zB -> statsB
  k_gin<64, false><<<96, 256, 0, stream>>>(zA, statsA, c1_g, c1_be, cv_eps,
      cv_w1, cv_b1, cv_w2, cv_b2, zB, partial, counter, statsB, nullptr, nullptr, nullptr);

  // GIN layer 3: read zB, write zA -> statsC
  k_gin<64, false><<<96, 256, 0, stream>>>(zB, statsB, cv_g, cv_be, cv_eps + 1,
      cv_w1 + HH*HH, cv_b1 + HH, cv_w2 + HH*HH, cv_b2 + HH, zA, partial, counter, statsC,
      nullptr, nullptr, nullptr);

  // head + edge-layer-1 factorization (f16 outputs)
  k_head<<<96, 256, 0, stream>>>(zA, statsC, cv_g + HH, cv_be + HH,
                                 lin1_w, lin1_b, lin2_w, lin2_b, nf,
                                 ep_w1, ep_b1, Ah, Bh);

  // edge MLP (swapped-operand MFMA, pipelined, resident weights)
  k_edges_f16<<<EBLK, 256, 0, stream>>>(Ah, Bh, Wf, ep_b2, ep_b3, ep_w4, ep_b4, out);

  // mirror lower triangle + zero diagonal
  k_mirror<<<1176, 256, 0, stream>>>(out);
}

// Round 6
// 119.706 us; speedup vs baseline: 2.6679x; 2.6679x over previous
//
#include <hip/hip_runtime.h>
#include <math.h>

#define NN 1536
#define FF 32
#define HH 64
#define EE (NN*(NN-1)/2)   // 1178880 = 73680 * 16
#define NGRP (EE/16)       // 73680 groups of 16 edges
#define GPW 8              // groups per wave; 2304 blocks * 4 waves * 8 = 73728
#define EBLK 2304
#define BN_EPS 1e-5f
#define SLOPE 0.01f

typedef _Float16 v8h  __attribute__((ext_vector_type(8)));
typedef float    f32x4 __attribute__((ext_vector_type(4)));
typedef float    f32x8 __attribute__((ext_vector_type(8)));

union V8H { v8h v; float4 f4; };

__device__ __forceinline__ float lrelu_f(float v){ return v >= 0.f ? v : SLOPE*v; }
__device__ __forceinline__ f32x4 lrelu4(f32x4 v) {
  f32x4 r;
#pragma unroll
  for (int j = 0; j < 4; ++j) r[j] = v[j] >= 0.f ? v[j] : SLOPE*v[j];
  return r;
}

// ---------------------------------------------------------------------------
// Fused GIN layer, NO cross-block communication (round-5's fence/atomic
// last-block reduction serialized on XCD L2 flushes: 1.2us x 96 blocks).
// Each block redundantly recomputes BN stats of zin with a vectorized pass
// (deterministic: identical summation order in every block), then:
//   h = (FIRST ? zin : lrelu(BN(zin))) ; u = (1+eps)h + exclusive prefix
//   zout = relu(relu(u@W1+b1)@W2+b2)
// FIRST launch has 16 extra blocks that pack the edge-MLP weights.
template<int DIN, bool FIRST>
__global__ __launch_bounds__(512) void k_gin(
    const float* __restrict__ zin,
    const float* __restrict__ gg, const float* __restrict__ be,
    const float* __restrict__ eps_p,
    const float* __restrict__ W1, const float* __restrict__ b1,
    const float* __restrict__ W2, const float* __restrict__ b2,
    float* __restrict__ zout,
    const float* __restrict__ pw2, const float* __restrict__ pw3,
    _Float16* __restrict__ pwf) {
  int bid = blockIdx.x, tid = threadIdx.x;
  if (FIRST && bid >= 96) {
    // edge-weight fragment prep (8192 elements over 16 blocks)
    int i = (bid - 96)*512 + tid;
    if (i < 8192) {
      int mat = i >> 12, r = i & 4095;
      int k = r >> 6, cout = r & 63;
      int m = cout >> 4, cc = cout & 15;
      int q, g, b;
      if (mat == 0) { q = k >> 5; g = (k >> 3) & 3; b = k & 7; }
      else { int mF = k >> 4; g = (k >> 2) & 3; int rr = k & 3; q = mF >> 1; b = ((mF & 1) << 2) | rr; }
      const float* W = mat ? pw3 : pw2;
      pwf[mat*4096 + ((q*4 + m)*64 + (g*16 + cc))*8 + b] = (_Float16)W[r];
    }
    return;
  }

  __shared__ float W1s[DIN*64];
  __shared__ float W2s[4096];
  __shared__ float red[2048];
  __shared__ float redq[2048];
  __shared__ float scl[64], sft[64], pf[64];
  __shared__ float hh[16][64];
  __shared__ float uls[16*64];
  __shared__ float t1s[16][64];

  int c = tid & 63, y = tid >> 6;          // y in 0..7
  for (int i = tid; i < DIN*64; i += 512) W1s[i] = W1[i];
  for (int i = tid; i < 4096; i += 512)   W2s[i] = W2[i];

  constexpr int C4 = DIN/4;                // float4 cols per row
  constexpr int RS = 512/C4;               // row-segments in flight
  int col4 = tid % C4, rseg = tid / C4;
  const f32x4* z4 = (const f32x4*)zin;
  int r0 = bid*16;

  // ---- stats pass (redundant per block; layers 2..3 only) ----
  if (!FIRST) {
    f32x4 s4 = {0.f,0.f,0.f,0.f}, q4 = {0.f,0.f,0.f,0.f};
    for (int n = rseg; n < NN; n += RS) {
      f32x4 v = z4[n*C4 + col4];
      s4 += v; q4 += v*v;
    }
#pragma unroll
    for (int j = 0; j < 4; ++j) {
      red[rseg*DIN + col4*4 + j]  = s4[j];
      redq[rseg*DIN + col4*4 + j] = q4[j];
    }
    __syncthreads();
    if (tid < DIN) {
      float S = 0.f, Q = 0.f;
      for (int r = 0; r < RS; ++r) { S += red[r*DIN + tid]; Q += redq[r*DIN + tid]; }
      float m  = S * (1.f/NN);
      float iv = rsqrtf(Q * (1.f/NN) - m*m + BN_EPS);
      float sc = iv * gg[tid];
      scl[tid] = sc;
      sft[tid] = be[tid] - m*sc;
    }
    __syncthreads();
  }

  // ---- prefix pass: pf[c] = sum_{n<r0} h[n][c] ----
  {
    f32x4 p4 = {0.f,0.f,0.f,0.f};
    f32x4 sc4, sh4;
    if (!FIRST) {
#pragma unroll
      for (int j = 0; j < 4; ++j) { sc4[j] = scl[col4*4 + j]; sh4[j] = sft[col4*4 + j]; }
    }
    for (int n = rseg; n < r0; n += RS) {
      f32x4 v = z4[n*C4 + col4];
      if (!FIRST) v = lrelu4(v*sc4 + sh4);
      p4 += v;
    }
#pragma unroll
    for (int j = 0; j < 4; ++j) red[rseg*DIN + col4*4 + j] = p4[j];
    __syncthreads();
    if (tid < DIN) {
      float S = 0.f;
      for (int r = 0; r < RS; ++r) S += red[r*DIN + tid];
      pf[tid] = S;
    }
    __syncthreads();
  }

  // ---- h tile + u (exclusive scan over the block's 16 rows) ----
  float e1 = 1.f + eps_p[0];
  if (c < DIN) {
    for (int rr = y; rr < 16; rr += 8) {
      float v = zin[(r0 + rr)*DIN + c];
      hh[rr][c] = FIRST ? v : lrelu_f(v*scl[c] + sft[c]);
    }
  }
  __syncthreads();
  if (c < DIN) {
    for (int rr = y; rr < 16; rr += 8) {
      float run = pf[c];
      for (int r2 = 0; r2 < rr; ++r2) run += hh[r2][c];
      uls[rr*DIN + c] = e1*hh[rr][c] + run;
    }
  }
  __syncthreads();

  // ---- matmul 1: t1 = relu(u @ W1 + b1), rows y and y+8 ----
  {
    float a0 = b1[c], a1 = a0;
    for (int k = 0; k < DIN; ++k) {
      float w = W1s[k*64 + c];
      a0 = fmaf(uls[y*DIN + k],       w, a0);
      a1 = fmaf(uls[(y + 8)*DIN + k], w, a1);
    }
    t1s[y][c]     = fmaxf(a0, 0.f);
    t1s[y + 8][c] = fmaxf(a1, 0.f);
  }
  __syncthreads();

  // ---- matmul 2: zout = relu(t1 @ W2 + b2) ----
  {
    float z0 = b2[c], z1 = z0;
    for (int k = 0; k < 64; ++k) {
      float w = W2s[k*64 + c];
      z0 = fmaf(t1s[y][k],     w, z0);
      z1 = fmaf(t1s[y + 8][k], w, z1);
    }
    zout[(r0 + y)*64 + c]     = fmaxf(z0, 0.f);
    zout[(r0 + y + 8)*64 + c] = fmaxf(z1, 0.f);
  }
}

// ---------------------------------------------------------------------------
// head: redundant stats of z; h3=lrelu(BN(z)); hf=lrelu(lrelu(h3@lin1)@lin2)+nf;
// A=hf@W1a+b1e; B=hf@W1b (f16 outputs for edge MFMA)
__global__ __launch_bounds__(512) void k_head(
    const float* __restrict__ z,
    const float* __restrict__ gg, const float* __restrict__ be,
    const float* __restrict__ l1w, const float* __restrict__ l1b,
    const float* __restrict__ l2w, const float* __restrict__ l2b,
    const float* __restrict__ nf,
    const float* __restrict__ epw1, const float* __restrict__ epb1,
    _Float16* __restrict__ Ah, _Float16* __restrict__ Bh) {
  __shared__ float W1s[4096];
  __shared__ float W2s[2048];
  __shared__ float Was[2048];
  __shared__ float Wbs[2048];
  __shared__ float scratch[4096];          // red/redq, then t0/t1/t2
  __shared__ float scl[64], sft[64];
  int tid = threadIdx.x, c = tid & 63, y = tid >> 6;
  for (int i = tid; i < 4096; i += 512) W1s[i] = l1w[i];
  for (int i = tid; i < 2048; i += 512) { W2s[i] = l2w[i]; Was[i] = epw1[i]; Wbs[i] = epw1[2048 + i]; }

  // ---- stats pass over z (redundant per block) ----
  {
    int col4 = tid & 15, rseg = tid >> 4;  // RS = 32
    const f32x4* z4 = (const f32x4*)z;
    f32x4 s4 = {0.f,0.f,0.f,0.f}, q4 = {0.f,0.f,0.f,0.f};
    for (int n = rseg; n < NN; n += 32) {
      f32x4 v = z4[n*16 + col4];
      s4 += v; q4 += v*v;
    }
    float* red  = scratch;
    float* redq = scratch + 2048;
#pragma unroll
    for (int j = 0; j < 4; ++j) {
      red[rseg*64 + col4*4 + j]  = s4[j];
      redq[rseg*64 + col4*4 + j] = q4[j];
    }
    __syncthreads();
    if (tid < 64) {
      float S = 0.f, Q = 0.f;
      for (int r = 0; r < 32; ++r) { S += red[r*64 + tid]; Q += redq[r*64 + tid]; }
      float m  = S * (1.f/NN);
      float iv = rsqrtf(Q * (1.f/NN) - m*m + BN_EPS);
      float sc = iv * gg[tid];
      scl[tid] = sc;
      sft[tid] = be[tid] - m*sc;
    }
    __syncthreads();
  }

  float* t0 = scratch;          // [16][64]
  float* t1 = scratch + 1024;   // [16][64]
  float* t2 = scratch + 2048;   // [16][32]
  int r0 = blockIdx.x*16;

  for (int rr = y; rr < 16; rr += 8)
    t0[rr*64 + c] = lrelu_f(z[(r0 + rr)*64 + c]*scl[c] + sft[c]);
  __syncthreads();
  {
    float a0 = l1b[c], a1 = a0;
    for (int k = 0; k < 64; ++k) {
      float w = W1s[k*64 + c];
      a0 = fmaf(t0[y*64 + k],       w, a0);
      a1 = fmaf(t0[(y + 8)*64 + k], w, a1);
    }
    t1[y*64 + c]       = lrelu_f(a0);
    t1[(y + 8)*64 + c] = lrelu_f(a1);
  }
  __syncthreads();
  if (c < 32) {
    float v0 = l2b[c], v1 = v0;
    for (int k = 0; k < 64; ++k) {
      float w = W2s[k*32 + c];
      v0 = fmaf(t1[y*64 + k],       w, v0);
      v1 = fmaf(t1[(y + 8)*64 + k], w, v1);
    }
    t2[y*32 + c]       = lrelu_f(v0) + nf[(r0 + y)*32 + c];
    t2[(y + 8)*32 + c] = lrelu_f(v1) + nf[(r0 + y + 8)*32 + c];
  }
  __syncthreads();
  {
    float av0 = epb1[c], av1 = av0;
    float bv0 = 0.f, bv1 = 0.f;
    for (int k = 0; k < 32; ++k) {
      float wa = Was[k*64 + c], wb = Wbs[k*64 + c];
      av0 = fmaf(t2[y*32 + k], wa, av0);       bv0 = fmaf(t2[y*32 + k], wb, bv0);
      av1 = fmaf(t2[(y + 8)*32 + k], wa, av1); bv1 = fmaf(t2[(y + 8)*32 + k], wb, bv1);
    }
    Ah[(r0 + y)*64 + c]     = (_Float16)av0;  Bh[(r0 + y)*64 + c]     = (_Float16)bv0;
    Ah[(r0 + y + 8)*64 + c] = (_Float16)av1;  Bh[(r0 + y + 8)*64 + c] = (_Float16)bv1;
  }
}

// ---------------------------------------------------------------------------
__device__ __forceinline__ int ebase(int s) { return s*(2*NN - 1 - s)/2; }

// edge MLP, swapped-operand MFMA. Lane (c,g): edge=c preserved across layers.
// launch_bounds(256,2): VGPR cap 256 keeps weights+biases resident.
__global__ __launch_bounds__(256, 2) void k_edges_f16(
    const _Float16* __restrict__ Ah, const _Float16* __restrict__ Bh,
    const _Float16* __restrict__ Wf,
    const float* __restrict__ b2, const float* __restrict__ b3,
    const float* __restrict__ w4, const float* __restrict__ b4,
    float* __restrict__ out) {
  int tid = threadIdx.x, wid = tid >> 6, lane = tid & 63;
  int c = lane & 15, g = lane >> 4;

  const v8h* wp = (const v8h*)Wf;
  v8h wv2[8], wv3[8];
#pragma unroll
  for (int f = 0; f < 8; ++f) { wv2[f] = wp[f*64 + lane]; wv3[f] = wp[512 + f*64 + lane]; }

  // biases pre-shaped as MFMA C-operands: b2v[m][r] = bias of feature 16m+4g+r
  f32x4 b2v[4], b3v[4], w4v[4];
  int g4 = g*4;
#pragma unroll
  for (int m = 0; m < 4; ++m)
#pragma unroll
    for (int r = 0; r < 4; ++r) {
      int f = 16*m + g4 + r;
      b2v[m][r] = b2[f]; b3v[m][r] = b3[f]; w4v[m][r] = w4[f];
    }
  float b4v = b4[0];

  V8H zu; zu.f4 = make_float4(0.f, 0.f, 0.f, 0.f);
  const v8h vzero = zu.v;

  int grp = (blockIdx.x*4 + wid)*GPW;
  if (grp >= NGRP) return;

  // initial decode of edge e = grp*16 + c -> (s,t)
  int e = grp*16 + c;
  float disc = (float)((2*NN-1)*(2*NN-1) - 8*e);
  int s = (int)((2.f*NN - 1.f - sqrtf(disc)) * 0.5f);
  if (s < 0) s = 0;
  if (s > NN-2) s = NN-2;
  while (s > 0 && e < ebase(s)) --s;
  while (e >= ebase(s+1)) ++s;
  int t = s + 1 + (e - ebase(s));

  // preload first group's activations
  V8H x0, x1, y0v, y1v;
  x0.f4  = *(const float4*)(Ah + s*64 + g*8);
  x1.f4  = *(const float4*)(Ah + s*64 + 32 + g*8);
  y0v.f4 = *(const float4*)(Bh + t*64 + g*8);
  y1v.f4 = *(const float4*)(Bh + t*64 + 32 + g*8);

  for (int it = 0; it < GPW; ++it, ++grp) {
    if (grp >= NGRP) break;
    int cs = s, ct = t;

    // consume prefetched activations -> L1 fragments
    V8H f0, f1;
    f0.v = __builtin_elementwise_max(x0.v + y0v.v, vzero);
    f1.v = __builtin_elementwise_max(x1.v + y1v.v, vzero);

    // advance + prefetch next group (last prefetch lands in Wf region: safe)
    t += 16;
    while (t >= NN && s < NN-1) { int o = t - NN; ++s; t = s + 1 + o; }
    x0.f4  = *(const float4*)(Ah + s*64 + g*8);
    x1.f4  = *(const float4*)(Ah + s*64 + 32 + g*8);
    y0v.f4 = *(const float4*)(Bh + t*64 + g*8);
    y1v.f4 = *(const float4*)(Bh + t*64 + 32 + g*8);

    // layer 2 (bias as C-operand)
    f32x4 acc[4];
#pragma unroll
    for (int m = 0; m < 4; ++m)
      acc[m] = __builtin_amdgcn_mfma_f32_16x16x32_f16(wv2[m],     f0.v, b2v[m], 0, 0, 0);
#pragma unroll
    for (int m = 0; m < 4; ++m)
      acc[m] = __builtin_amdgcn_mfma_f32_16x16x32_f16(wv2[4 + m], f1.v, acc[m], 0, 0, 0);

    // relu + pack to f16 (D-layout feeds layer-3 B-frags directly)
    f32x8 q0, q1;
#pragma unroll
    for (int r = 0; r < 4; ++r) {
      q0[r]     = fmaxf(acc[0][r], 0.f);
      q0[4 + r] = fmaxf(acc[1][r], 0.f);
      q1[r]     = fmaxf(acc[2][r], 0.f);
      q1[4 + r] = fmaxf(acc[3][r], 0.f);
    }
    v8h p0 = __builtin_convertvector(q0, v8h);
    v8h p1 = __builtin_convertvector(q1, v8h);

    // layer 3
    f32x4 acc3[4];
#pragma unroll
    for (int m = 0; m < 4; ++m)
      acc3[m] = __builtin_amdgcn_mfma_f32_16x16x32_f16(wv3[m],     p0, b3v[m], 0, 0, 0);
#pragma unroll
    for (int m = 0; m < 4; ++m)
      acc3[m] = __builtin_amdgcn_mfma_f32_16x16x32_f16(wv3[4 + m], p1, acc3[m], 0, 0, 0);

    // layer 4 + reduce over g
    float p = 0.f;
#pragma unroll
    for (int m = 0; m < 4; ++m)
#pragma unroll
      for (int r = 0; r < 4; ++r)
        p = fmaf(fmaxf(acc3[m][r], 0.f), w4v[m][r], p);
    p += __shfl_xor(p, 16, 64);
    p += __shfl_xor(p, 32, 64);
    float ez = __builtin_amdgcn_exp2f(-1.44269504f * (p + b4v));
    float prob = __builtin_amdgcn_rcpf(1.f + ez);
    if (lane < 16) out[cs*NN + ct] = prob;   // upper triangle, coalesced
  }
}

// mirror: lower = upper^T, diag = 0. Triangular grid (bi >= bj).
__global__ __launch_bounds__(256) void k_mirror(float* __restrict__ out) {
  __shared__ float tile[32][33];
  int k = blockIdx.x;
  int bi = (int)((sqrtf(8.f*k + 1.f) - 1.f)*0.5f);
  while (bi*(bi + 1)/2 > k) --bi;
  while ((bi + 1)*(bi + 2)/2 <= k) ++bi;
  int bj = k - bi*(bi + 1)/2;
  int i0 = bi*32, j0 = bj*32;
  int tx = threadIdx.x & 31, ty = threadIdx.x >> 5;   // 32 x 8
#pragma unroll
  for (int r = 0; r < 4; ++r)
    tile[ty + r*8][tx] = out[(j0 + ty + r*8)*NN + i0 + tx];
  __syncthreads();
#pragma unroll
  for (int r = 0; r < 4; ++r) {
    int row = ty + r*8;
    int i = i0 + row, j = j0 + tx;
    if (bi > bj)      out[i*NN + j] = tile[tx][row];
    else if (i > j)   out[i*NN + j] = tile[tx][row];
    else if (i == j)  out[i*NN + j] = 0.f;
  }
}

// ---------------------------------------------------------------------------
extern "C" void kernel_launch(void* const* d_in, const int* in_sizes, int n_in,
                              void* d_out, int out_size, void* d_ws, size_t ws_size,
                              hipStream_t stream) {
  const float* nf     = (const float*)d_in[1];
  const float* c1_eps = (const float*)d_in[2];
  const float* c1_w1  = (const float*)d_in[3];
  const float* c1_b1  = (const float*)d_in[4];
  const float* c1_w2  = (const float*)d_in[5];
  const float* c1_b2  = (const float*)d_in[6];
  const float* c1_g   = (const float*)d_in[7];
  const float* c1_be  = (const float*)d_in[8];
  const float* cv_eps = (const float*)d_in[9];
  const float* cv_w1  = (const float*)d_in[10];
  const float* cv_b1  = (const float*)d_in[11];
  const float* cv_w2  = (const float*)d_in[12];
  const float* cv_b2  = (const float*)d_in[13];
  const float* cv_g   = (const float*)d_in[14];
  const float* cv_be  = (const float*)d_in[15];
  const float* lin1_w = (const float*)d_in[16];
  const float* lin1_b = (const float*)d_in[17];
  const float* lin2_w = (const float*)d_in[18];
  const float* lin2_b = (const float*)d_in[19];
  const float* ep_w1  = (const float*)d_in[20];
  const float* ep_b1  = (const float*)d_in[21];
  const float* ep_w2  = (const float*)d_in[22];
  const float* ep_b2  = (const float*)d_in[23];
  const float* ep_w3  = (const float*)d_in[24];
  const float* ep_b3  = (const float*)d_in[25];
  const float* ep_w4  = (const float*)d_in[26];
  const float* ep_b4  = (const float*)d_in[27];

  float* ws = (float*)d_ws;
  float* zA    = ws;                     // [NN*64]
  float* zB    = zA + NN*64;             // [NN*64]
  _Float16* Ah = (_Float16*)(zB + NN*64);   // [NN*64] f16
  _Float16* Bh = Ah + NN*64;                // [NN*64] f16
  _Float16* Wf = Bh + NN*64;                // [2*4096] f16 (absorbs Bh prefetch overread)

  float* out = (float*)d_out;

  // GIN layer 1 (F=32 -> H=64); blocks 96..111 pack edge weights
  k_gin<32, true><<<112, 512, 0, stream>>>(nf, nullptr, nullptr, c1_eps,
      c1_w1, c1_b1, c1_w2, c1_b2, zA, ep_w2, ep_w3, Wf);

  // GIN layer 2 (stats of zA recomputed in-kernel; BN params = c1_g/c1_be)
  k_gin<64, false><<<96, 512, 0, stream>>>(zA, c1_g, c1_be, cv_eps,
      cv_w1, cv_b1, cv_w2, cv_b2, zB, nullptr, nullptr, nullptr);

  // GIN layer 3
  k_gin<64, false><<<96, 512, 0, stream>>>(zB, cv_g, cv_be, cv_eps + 1,
      cv_w1 + HH*HH, cv_b1 + HH, cv_w2 + HH*HH, cv_b2 + HH, zA,
      nullptr, nullptr, nullptr);

  // head + edge-layer-1 factorization (f16 outputs)
  k_head<<<96, 512, 0, stream>>>(zA, cv_g + HH, cv_be + HH,
                                 lin1_w, lin1_b, lin2_w, lin2_b, nf,
                                 ep_w1, ep_b1, Ah, Bh);

  // edge MLP (swapped-operand MFMA, pipelined, resident weights)
  k_edges_f16<<<EBLK, 256, 0, stream>>>(Ah, Bh, Wf, ep_b2, ep_b3, ep_w4, ep_b4, out);

  // mirror lower triangle + zero diagonal
  k_mirror<<<1176, 256, 0, stream>>>(out);
}

// Round 8
// 119.400 us; speedup vs baseline: 2.6747x; 1.0026x over previous
//
#include <hip/hip_runtime.h>
#include <math.h>

#define NN 1536
#define FF 32
#define HH 64
#define EE (NN*(NN-1)/2)
#define EBLK 2493          // 2493 blocks * 4 waves = 9972 = exact padded chunk count
#define BN_EPS 1e-5f
#define SLOPE 0.01f

typedef _Float16 v8h  __attribute__((ext_vector_type(8)));
typedef __fp16   v2hf __attribute__((ext_vector_type(2)));
typedef float    f32x4 __attribute__((ext_vector_type(4)));

union V8H { v8h v; v2hf h2[4]; float4 f4; };

__device__ __forceinline__ float lrelu_f(float v){ return v >= 0.f ? v : SLOPE*v; }
__device__ __forceinline__ f32x4 lrelu4(f32x4 v) {
  f32x4 r;
#pragma unroll
  for (int j = 0; j < 4; ++j) r[j] = v[j] >= 0.f ? v[j] : SLOPE*v[j];
  return r;
}

// ---------------------------------------------------------------------------
// Fused GIN layer (round-6 structure: no cross-block comm, redundant
// deterministic stats, vectorized passes).
template<int DIN, bool FIRST>
__global__ __launch_bounds__(512) void k_gin(
    const float* __restrict__ zin,
    const float* __restrict__ gg, const float* __restrict__ be,
    const float* __restrict__ eps_p,
    const float* __restrict__ W1, const float* __restrict__ b1,
    const float* __restrict__ W2, const float* __restrict__ b2,
    float* __restrict__ zout,
    const float* __restrict__ pw2, const float* __restrict__ pw3,
    _Float16* __restrict__ pwf) {
  int bid = blockIdx.x, tid = threadIdx.x;
  if (FIRST && bid >= 96) {
    int i = (bid - 96)*512 + tid;
    if (i < 8192) {
      int mat = i >> 12, r = i & 4095;
      int k = r >> 6, cout = r & 63;
      int m = cout >> 4, cc = cout & 15;
      int q, g, b;
      if (mat == 0) { q = k >> 5; g = (k >> 3) & 3; b = k & 7; }
      else { int mF = k >> 4; g = (k >> 2) & 3; int rr = k & 3; q = mF >> 1; b = ((mF & 1) << 2) | rr; }
      const float* W = mat ? pw3 : pw2;
      pwf[mat*4096 + ((q*4 + m)*64 + (g*16 + cc))*8 + b] = (_Float16)W[r];
    }
    return;
  }

  __shared__ float W1s[DIN*64];
  __shared__ float W2s[4096];
  __shared__ float red[2048];
  __shared__ float redq[2048];
  __shared__ float scl[64], sft[64], pf[64];
  __shared__ float hh[16][64];
  __shared__ float uls[16*64];
  __shared__ float t1s[16][64];

  int c = tid & 63, y = tid >> 6;
  for (int i = tid; i < DIN*64; i += 512) W1s[i] = W1[i];
  for (int i = tid; i < 4096; i += 512)   W2s[i] = W2[i];

  constexpr int C4 = DIN/4;
  constexpr int RS = 512/C4;
  int col4 = tid % C4, rseg = tid / C4;
  const f32x4* z4 = (const f32x4*)zin;
  int r0 = bid*16;

  if (!FIRST) {
    f32x4 s4 = {0.f,0.f,0.f,0.f}, q4 = {0.f,0.f,0.f,0.f};
    for (int n = rseg; n < NN; n += RS) {
      f32x4 v = z4[n*C4 + col4];
      s4 += v; q4 += v*v;
    }
#pragma unroll
    for (int j = 0; j < 4; ++j) {
      red[rseg*DIN + col4*4 + j]  = s4[j];
      redq[rseg*DIN + col4*4 + j] = q4[j];
    }
    __syncthreads();
    if (tid < DIN) {
      float S = 0.f, Q = 0.f;
      for (int r = 0; r < RS; ++r) { S += red[r*DIN + tid]; Q += redq[r*DIN + tid]; }
      float m  = S * (1.f/NN);
      float iv = rsqrtf(Q * (1.f/NN) - m*m + BN_EPS);
      float sc = iv * gg[tid];
      scl[tid] = sc;
      sft[tid] = be[tid] - m*sc;
    }
    __syncthreads();
  }

  {
    f32x4 p4 = {0.f,0.f,0.f,0.f};
    f32x4 sc4, sh4;
    if (!FIRST) {
#pragma unroll
      for (int j = 0; j < 4; ++j) { sc4[j] = scl[col4*4 + j]; sh4[j] = sft[col4*4 + j]; }
    }
    for (int n = rseg; n < r0; n += RS) {
      f32x4 v = z4[n*C4 + col4];
      if (!FIRST) v = lrelu4(v*sc4 + sh4);
      p4 += v;
    }
#pragma unroll
    for (int j = 0; j < 4; ++j) red[rseg*DIN + col4*4 + j] = p4[j];
    __syncthreads();
    if (tid < DIN) {
      float S = 0.f;
      for (int r = 0; r < RS; ++r) S += red[r*DIN + tid];
      pf[tid] = S;
    }
    __syncthreads();
  }

  float e1 = 1.f + eps_p[0];
  if (c < DIN) {
    for (int rr = y; rr < 16; rr += 8) {
      float v = zin[(r0 + rr)*DIN + c];
      hh[rr][c] = FIRST ? v : lrelu_f(v*scl[c] + sft[c]);
    }
  }
  __syncthreads();
  if (c < DIN) {
    for (int rr = y; rr < 16; rr += 8) {
      float run = pf[c];
      for (int r2 = 0; r2 < rr; ++r2) run += hh[r2][c];
      uls[rr*DIN + c] = e1*hh[rr][c] + run;
    }
  }
  __syncthreads();

  {
    float a0 = b1[c], a1 = a0;
    for (int k = 0; k < DIN; ++k) {
      float w = W1s[k*64 + c];
      a0 = fmaf(uls[y*DIN + k],       w, a0);
      a1 = fmaf(uls[(y + 8)*DIN + k], w, a1);
    }
    t1s[y][c]     = fmaxf(a0, 0.f);
    t1s[y + 8][c] = fmaxf(a1, 0.f);
  }
  __syncthreads();

  {
    float z0 = b2[c], z1 = z0;
    for (int k = 0; k < 64; ++k) {
      float w = W2s[k*64 + c];
      z0 = fmaf(t1s[y][k],     w, z0);
      z1 = fmaf(t1s[y + 8][k], w, z1);
    }
    zout[(r0 + y)*64 + c]     = fmaxf(z0, 0.f);
    zout[(r0 + y + 8)*64 + c] = fmaxf(z1, 0.f);
  }
}

// ---------------------------------------------------------------------------
// head (unchanged)
__global__ __launch_bounds__(512) void k_head(
    const float* __restrict__ z,
    const float* __restrict__ gg, const float* __restrict__ be,
    const float* __restrict__ l1w, const float* __restrict__ l1b,
    const float* __restrict__ l2w, const float* __restrict__ l2b,
    const float* __restrict__ nf,
    const float* __restrict__ epw1, const float* __restrict__ epb1,
    _Float16* __restrict__ Ah, _Float16* __restrict__ Bh) {
  __shared__ float W1s[4096];
  __shared__ float W2s[2048];
  __shared__ float Was[2048];
  __shared__ float Wbs[2048];
  __shared__ float scratch[4096];
  __shared__ float scl[64], sft[64];
  int tid = threadIdx.x, c = tid & 63, y = tid >> 6;
  for (int i = tid; i < 4096; i += 512) W1s[i] = l1w[i];
  for (int i = tid; i < 2048; i += 512) { W2s[i] = l2w[i]; Was[i] = epw1[i]; Wbs[i] = epw1[2048 + i]; }

  {
    int col4 = tid & 15, rseg = tid >> 4;
    const f32x4* z4 = (const f32x4*)z;
    f32x4 s4 = {0.f,0.f,0.f,0.f}, q4 = {0.f,0.f,0.f,0.f};
    for (int n = rseg; n < NN; n += 32) {
      f32x4 v = z4[n*16 + col4];
      s4 += v; q4 += v*v;
    }
    float* red  = scratch;
    float* redq = scratch + 2048;
#pragma unroll
    for (int j = 0; j < 4; ++j) {
      red[rseg*64 + col4*4 + j]  = s4[j];
      redq[rseg*64 + col4*4 + j] = q4[j];
    }
    __syncthreads();
    if (tid < 64) {
      float S = 0.f, Q = 0.f;
      for (int r = 0; r < 32; ++r) { S += red[r*64 + tid]; Q += redq[r*64 + tid]; }
      float m  = S * (1.f/NN);
      float iv = rsqrtf(Q * (1.f/NN) - m*m + BN_EPS);
      float sc = iv * gg[tid];
      scl[tid] = sc;
      sft[tid] = be[tid] - m*sc;
    }
    __syncthreads();
  }

  float* t0 = scratch;
  float* t1 = scratch + 1024;
  float* t2 = scratch + 2048;
  int r0 = blockIdx.x*16;

  for (int rr = y; rr < 16; rr += 8)
    t0[rr*64 + c] = lrelu_f(z[(r0 + rr)*64 + c]*scl[c] + sft[c]);
  __syncthreads();
  {
    float a0 = l1b[c], a1 = a0;
    for (int k = 0; k < 64; ++k) {
      float w = W1s[k*64 + c];
      a0 = fmaf(t0[y*64 + k],       w, a0);
      a1 = fmaf(t0[(y + 8)*64 + k], w, a1);
    }
    t1[y*64 + c]       = lrelu_f(a0);
    t1[(y + 8)*64 + c] = lrelu_f(a1);
  }
  __syncthreads();
  if (c < 32) {
    float v0 = l2b[c], v1 = v0;
    for (int k = 0; k < 64; ++k) {
      float w = W2s[k*32 + c];
      v0 = fmaf(t1[y*64 + k],       w, v0);
      v1 = fmaf(t1[(y + 8)*64 + k], w, v1);
    }
    t2[y*32 + c]       = lrelu_f(v0) + nf[(r0 + y)*32 + c];
    t2[(y + 8)*32 + c] = lrelu_f(v1) + nf[(r0 + y + 8)*32 + c];
  }
  __syncthreads();
  {
    float av0 = epb1[c], av1 = av0;
    float bv0 = 0.f, bv1 = 0.f;
    for (int k = 0; k < 32; ++k) {
      float wa = Was[k*64 + c], wb = Wbs[k*64 + c];
      av0 = fmaf(t2[y*32 + k], wa, av0);       bv0 = fmaf(t2[y*32 + k], wb, bv0);
      av1 = fmaf(t2[(y + 8)*32 + k], wa, av1); bv1 = fmaf(t2[(y + 8)*32 + k], wb, bv1);
    }
    Ah[(r0 + y)*64 + c]     = (_Float16)av0;  Bh[(r0 + y)*64 + c]     = (_Float16)bv0;
    Ah[(r0 + y + 8)*64 + c] = (_Float16)av1;  Bh[(r0 + y + 8)*64 + c] = (_Float16)bv1;
  }
}

// ---------------------------------------------------------------------------
// Edge MLP, row-tiled: wave = (s, 128-col chunk). s wave-uniform, A[s] frags
// hoisted; advance = t0+=16 + uniform break. 9972 waves cover the padded
// triangle (bands: 127 rows x 12 chunks, then 128-row bands of 11..1).
__global__ __launch_bounds__(256, 2) void k_edges_f16(
    const _Float16* __restrict__ Ah, const _Float16* __restrict__ Bh,
    const _Float16* __restrict__ Wf,
    const float* __restrict__ b2, const float* __restrict__ b3,
    const float* __restrict__ w4, const float* __restrict__ b4,
    float* __restrict__ out) {
  int tid = threadIdx.x, wid = tid >> 6, lane = tid & 63;
  int c = lane & 15, g = lane >> 4;

  // ---- wave -> (s, chunk) band decode (uniform per wave) ----
  int w = blockIdx.x*4 + wid;
  int cum, kk, sbase;
  if (w < 1524) { cum = 0; kk = 12; sbase = 0; }
  else {
    cum = 1524; kk = 11; sbase = 127;
    while (kk > 1 && w >= cum + 128*kk) { cum += 128*kk; sbase += 128; --kk; }
  }
  int idx = w - cum;
  int q = idx / kk;
  int s = sbase + q;
  int t0 = s + 1 + ((idx - q*kk) << 7);

  // ---- resident weights / biases ----
  const v8h* wp = (const v8h*)Wf;
  v8h wv2[8], wv3[8];
#pragma unroll
  for (int f = 0; f < 8; ++f) { wv2[f] = wp[f*64 + lane]; wv3[f] = wp[512 + f*64 + lane]; }

  f32x4 b2v[4], b3v[4], w4v[4];
  int g4 = g*4;
#pragma unroll
  for (int m = 0; m < 4; ++m)
#pragma unroll
    for (int r = 0; r < 4; ++r) {
      int f = 16*m + g4 + r;
      b2v[m][r] = b2[f]; b3v[m][r] = b3[f]; w4v[m][r] = w4[f];
    }
  float b4v = b4[0];

  V8H zu; zu.f4 = make_float4(0.f, 0.f, 0.f, 0.f);
  const v8h vzero = zu.v;

  // ---- A[s] fragments: loop-invariant ----
  V8H a0, a1;
  a0.f4 = *(const float4*)(Ah + s*64 + g*8);
  a1.f4 = *(const float4*)(Ah + s*64 + 32 + g*8);

  // ---- first B prefetch ----
  int tl = min(t0 + c, NN - 1);
  V8H y0, y1;
  y0.f4 = *(const float4*)(Bh + tl*64 + g*8);
  y1.f4 = *(const float4*)(Bh + tl*64 + 32 + g*8);

  for (int it = 0; it < 8; ++it) {
    int tb = t0 + (it << 4);
    if (tb >= NN) break;               // uniform
    int t = tb + c;

    V8H f0, f1;
    f0.v = __builtin_elementwise_max(a0.v + y0.v, vzero);
    f1.v = __builtin_elementwise_max(a1.v + y1.v, vzero);

    // prefetch next group's B rows (clamped; safe overread)
    int tn = min(tb + 16 + c, NN - 1);
    y0.f4 = *(const float4*)(Bh + tn*64 + g*8);
    y1.f4 = *(const float4*)(Bh + tn*64 + 32 + g*8);

    // layer 2 (bias as C-operand)
    __builtin_amdgcn_s_setprio(1);
    f32x4 acc[4];
#pragma unroll
    for (int m = 0; m < 4; ++m)
      acc[m] = __builtin_amdgcn_mfma_f32_16x16x32_f16(wv2[m],     f0.v, b2v[m], 0, 0, 0);
#pragma unroll
    for (int m = 0; m < 4; ++m)
      acc[m] = __builtin_amdgcn_mfma_f32_16x16x32_f16(wv2[4 + m], f1.v, acc[m], 0, 0, 0);
    __builtin_amdgcn_s_setprio(0);

    // relu (f32) + pack via v_cvt_pkrtz (D-layout feeds layer-3 B-frags)
    V8H p0, p1;
#pragma unroll
    for (int m = 0; m < 2; ++m) {
      p0.h2[2*m]     = __builtin_amdgcn_cvt_pkrtz(fmaxf(acc[m][0], 0.f),   fmaxf(acc[m][1], 0.f));
      p0.h2[2*m + 1] = __builtin_amdgcn_cvt_pkrtz(fmaxf(acc[m][2], 0.f),   fmaxf(acc[m][3], 0.f));
      p1.h2[2*m]     = __builtin_amdgcn_cvt_pkrtz(fmaxf(acc[m+2][0], 0.f), fmaxf(acc[m+2][1], 0.f));
      p1.h2[2*m + 1] = __builtin_amdgcn_cvt_pkrtz(fmaxf(acc[m+2][2], 0.f), fmaxf(acc[m+2][3], 0.f));
    }

    // layer 3
    __builtin_amdgcn_s_setprio(1);
    f32x4 acc3[4];
#pragma unroll
    for (int m = 0; m < 4; ++m)
      acc3[m] = __builtin_amdgcn_mfma_f32_16x16x32_f16(wv3[m],     p0.v, b3v[m], 0, 0, 0);
#pragma unroll
    for (int m = 0; m < 4; ++m)
      acc3[m] = __builtin_amdgcn_mfma_f32_16x16x32_f16(wv3[4 + m], p1.v, acc3[m], 0, 0, 0);
    __builtin_amdgcn_s_setprio(0);

    // layer 4 + reduce over g
    float p = 0.f;
#pragma unroll
    for (int m = 0; m < 4; ++m)
#pragma unroll
      for (int r = 0; r < 4; ++r)
        p = fmaf(fmaxf(acc3[m][r], 0.f), w4v[m][r], p);
    p += __shfl_xor(p, 16, 64);
    p += __shfl_xor(p, 32, 64);
    float ez = __builtin_amdgcn_exp2f(-1.44269504f * (p + b4v));
    float prob = __builtin_amdgcn_rcpf(1.f + ez);
    if (lane < 16 && t < NN) out[s*NN + t] = prob;   // upper triangle, coalesced
  }
}

// mirror: lower = upper^T, diag = 0. Triangular grid.
__global__ __launch_bounds__(256) void k_mirror(float* __restrict__ out) {
  __shared__ float tile[32][33];
  int k = blockIdx.x;
  int bi = (int)((sqrtf(8.f*k + 1.f) - 1.f)*0.5f);
  while (bi*(bi + 1)/2 > k) --bi;
  while ((bi + 1)*(bi + 2)/2 <= k) ++bi;
  int bj = k - bi*(bi + 1)/2;
  int i0 = bi*32, j0 = bj*32;
  int tx = threadIdx.x & 31, ty = threadIdx.x >> 5;
#pragma unroll
  for (int r = 0; r < 4; ++r)
    tile[ty + r*8][tx] = out[(j0 + ty + r*8)*NN + i0 + tx];
  __syncthreads();
#pragma unroll
  for (int r = 0; r < 4; ++r) {
    int row = ty + r*8;
    int i = i0 + row, j = j0 + tx;
    if (bi > bj)      out[i*NN + j] = tile[tx][row];
    else if (i > j)   out[i*NN + j] = tile[tx][row];
    else if (i == j)  out[i*NN + j] = 0.f;
  }
}

// ---------------------------------------------------------------------------
extern "C" void kernel_launch(void* const* d_in, const int* in_sizes, int n_in,
                              void* d_out, int out_size, void* d_ws, size_t ws_size,
                              hipStream_t stream) {
  const float* nf     = (const float*)d_in[1];
  const float* c1_eps = (const float*)d_in[2];
  const float* c1_w1  = (const float*)d_in[3];
  const float* c1_b1  = (const float*)d_in[4];
  const float* c1_w2  = (const float*)d_in[5];
  const float* c1_b2  = (const float*)d_in[6];
  const float* c1_g   = (const float*)d_in[7];
  const float* c1_be  = (const float*)d_in[8];
  const float* cv_eps = (const float*)d_in[9];
  const float* cv_w1  = (const float*)d_in[10];
  const float* cv_b1  = (const float*)d_in[11];
  const float* cv_w2  = (const float*)d_in[12];
  const float* cv_b2  = (const float*)d_in[13];
  const float* cv_g   = (const float*)d_in[14];
  const float* cv_be  = (const float*)d_in[15];
  const float* lin1_w = (const float*)d_in[16];
  const float* lin1_b = (const float*)d_in[17];
  const float* lin2_w = (const float*)d_in[18];
  const float* lin2_b = (const float*)d_in[19];
  const float* ep_w1  = (const float*)d_in[20];
  const float* ep_b1  = (const float*)d_in[21];
  const float* ep_w2  = (const float*)d_in[22];
  const float* ep_b2  = (const float*)d_in[23];
  const float* ep_w3  = (const float*)d_in[24];
  const float* ep_b3  = (const float*)d_in[25];
  const float* ep_w4  = (const float*)d_in[26];
  const float* ep_b4  = (const float*)d_in[27];

  float* ws = (float*)d_ws;
  float* zA    = ws;
  float* zB    = zA + NN*64;
  _Float16* Ah = (_Float16*)(zB + NN*64);
  _Float16* Bh = Ah + NN*64;
  _Float16* Wf = Bh + NN*64;   // absorbs Bh prefetch overread

  float* out = (float*)d_out;

  k_gin<32, true><<<112, 512, 0, stream>>>(nf, nullptr, nullptr, c1_eps,
      c1_w1, c1_b1, c1_w2, c1_b2, zA, ep_w2, ep_w3, Wf);

  k_gin<64, false><<<96, 512, 0, stream>>>(zA, c1_g, c1_be, cv_eps,
      cv_w1, cv_b1, cv_w2, cv_b2, zB, nullptr, nullptr, nullptr);

  k_gin<64, false><<<96, 512, 0, stream>>>(zB, cv_g, cv_be, cv_eps + 1,
      cv_w1 + HH*HH, cv_b1 + HH, cv_w2 + HH*HH, cv_b2 + HH, zA,
      nullptr, nullptr, nullptr);

  k_head<<<96, 512, 0, stream>>>(zA, cv_g + HH, cv_be + HH,
                                 lin1_w, lin1_b, lin2_w, lin2_b, nf,
                                 ep_w1, ep_b1, Ah, Bh);

  k_edges_f16<<<EBLK, 256, 0, stream>>>(Ah, Bh, Wf, ep_b2, ep_b3, ep_w4, ep_b4, out);

  k_mirror<<<1176, 256, 0, stream>>>(out);
}

// Round 9
// 94.459 us; speedup vs baseline: 3.3810x; 1.2640x over previous
//
#include <hip/hip_runtime.h>
#include <math.h>

#define NN 1536
#define FF 32
#define HH 64
#define EE (NN*(NN-1)/2)
#define EBLK 2493          // 2493 blocks * 4 waves = 9972 = exact padded chunk count
#define BN_EPS 1e-5f
#define SLOPE 0.01f

typedef _Float16 v8h  __attribute__((ext_vector_type(8)));
typedef __fp16   v2hf __attribute__((ext_vector_type(2)));
typedef float    f32x4 __attribute__((ext_vector_type(4)));

union V8H { v8h v; v2hf h2[4]; float4 f4; };

__device__ __forceinline__ float lrelu_f(float v){ return v >= 0.f ? v : SLOPE*v; }
__device__ __forceinline__ f32x4 lrelu4(f32x4 v) {
  f32x4 r;
#pragma unroll
  for (int j = 0; j < 4; ++j) r[j] = v[j] >= 0.f ? v[j] : SLOPE*v[j];
  return r;
}

// ---------------------------------------------------------------------------
// Fused GIN layer. No cross-block comm; redundant deterministic stats.
// Sweeps use multi-accumulator unrolling to keep 2-4 loads in flight
// (round-8 diagnosis: serial L2-latency chains dominated these kernels).
template<int DIN, bool FIRST>
__global__ __launch_bounds__(512) void k_gin(
    const float* __restrict__ zin,
    const float* __restrict__ gg, const float* __restrict__ be,
    const float* __restrict__ eps_p,
    const float* __restrict__ W1, const float* __restrict__ b1,
    const float* __restrict__ W2, const float* __restrict__ b2,
    float* __restrict__ zout,
    const float* __restrict__ pw2, const float* __restrict__ pw3,
    _Float16* __restrict__ pwf) {
  int bid = blockIdx.x, tid = threadIdx.x;
  if (FIRST && bid >= 96) {
    int i = (bid - 96)*512 + tid;
    if (i < 8192) {
      int mat = i >> 12, r = i & 4095;
      int k = r >> 6, cout = r & 63;
      int m = cout >> 4, cc = cout & 15;
      int q, g, b;
      if (mat == 0) { q = k >> 5; g = (k >> 3) & 3; b = k & 7; }
      else { int mF = k >> 4; g = (k >> 2) & 3; int rr = k & 3; q = mF >> 1; b = ((mF & 1) << 2) | rr; }
      const float* W = mat ? pw3 : pw2;
      pwf[mat*4096 + ((q*4 + m)*64 + (g*16 + cc))*8 + b] = (_Float16)W[r];
    }
    return;
  }

  __shared__ float W1s[DIN*64];
  __shared__ float W2s[4096];
  __shared__ float red[2048];
  __shared__ float redq[2048];
  __shared__ float scl[64], sft[64], pf[64];
  __shared__ float hh[16][64];
  __shared__ float uls[16*64];
  __shared__ float t1s[16][64];

  int c = tid & 63, y = tid >> 6;
  for (int i = tid; i < DIN*64; i += 512) W1s[i] = W1[i];
  for (int i = tid; i < 4096; i += 512)   W2s[i] = W2[i];

  constexpr int C4 = DIN/4;
  constexpr int RS = 512/C4;
  int col4 = tid % C4, rseg = tid / C4;
  const f32x4* z4 = (const f32x4*)zin;
  int r0 = bid*16;

  if (!FIRST) {
    // stats sweep, 4 loads in flight (NN % (4*RS) == 0 for DIN=64)
    f32x4 s0 = {0.f,0.f,0.f,0.f}, s1 = s0, s2 = s0, s3 = s0;
    f32x4 q0 = s0, q1 = s0, q2 = s0, q3 = s0;
    for (int n = rseg; n < NN; n += 4*RS) {
      f32x4 v0 = z4[n*C4 + col4];
      f32x4 v1 = z4[(n + RS)*C4 + col4];
      f32x4 v2 = z4[(n + 2*RS)*C4 + col4];
      f32x4 v3 = z4[(n + 3*RS)*C4 + col4];
      s0 += v0; q0 += v0*v0;
      s1 += v1; q1 += v1*v1;
      s2 += v2; q2 += v2*v2;
      s3 += v3; q3 += v3*v3;
    }
    f32x4 s4 = (s0 + s1) + (s2 + s3);
    f32x4 q4 = (q0 + q1) + (q2 + q3);
#pragma unroll
    for (int j = 0; j < 4; ++j) {
      red[rseg*DIN + col4*4 + j]  = s4[j];
      redq[rseg*DIN + col4*4 + j] = q4[j];
    }
    __syncthreads();
    if (tid < DIN) {
      float S = 0.f, Q = 0.f;
      for (int r = 0; r < RS; ++r) { S += red[r*DIN + tid]; Q += redq[r*DIN + tid]; }
      float m  = S * (1.f/NN);
      float iv = rsqrtf(Q * (1.f/NN) - m*m + BN_EPS);
      float sc = iv * gg[tid];
      scl[tid] = sc;
      sft[tid] = be[tid] - m*sc;
    }
    __syncthreads();
  }

  {
    // prefix sweep, 2 loads in flight
    f32x4 p0 = {0.f,0.f,0.f,0.f}, p1 = p0;
    f32x4 sc4, sh4;
    if (!FIRST) {
#pragma unroll
      for (int j = 0; j < 4; ++j) { sc4[j] = scl[col4*4 + j]; sh4[j] = sft[col4*4 + j]; }
    }
    int n = rseg;
    for (; n + RS < r0; n += 2*RS) {
      f32x4 va = z4[n*C4 + col4];
      f32x4 vb = z4[(n + RS)*C4 + col4];
      if (!FIRST) { va = lrelu4(va*sc4 + sh4); vb = lrelu4(vb*sc4 + sh4); }
      p0 += va; p1 += vb;
    }
    for (; n < r0; n += RS) {
      f32x4 va = z4[n*C4 + col4];
      if (!FIRST) va = lrelu4(va*sc4 + sh4);
      p0 += va;
    }
    p0 += p1;
#pragma unroll
    for (int j = 0; j < 4; ++j) red[rseg*DIN + col4*4 + j] = p0[j];
    __syncthreads();
    if (tid < DIN) {
      float S = 0.f;
      for (int r = 0; r < RS; ++r) S += red[r*DIN + tid];
      pf[tid] = S;
    }
    __syncthreads();
  }

  float e1 = 1.f + eps_p[0];
  if (c < DIN) {
    for (int rr = y; rr < 16; rr += 8) {
      float v = zin[(r0 + rr)*DIN + c];
      hh[rr][c] = FIRST ? v : lrelu_f(v*scl[c] + sft[c]);
    }
  }
  __syncthreads();
  if (c < DIN) {
    for (int rr = y; rr < 16; rr += 8) {
      float run = pf[c];
      for (int r2 = 0; r2 < rr; ++r2) run += hh[r2][c];
      uls[rr*DIN + c] = e1*hh[rr][c] + run;
    }
  }
  __syncthreads();

  {
    float a0 = b1[c], a1 = a0;
    for (int k = 0; k < DIN; ++k) {
      float w = W1s[k*64 + c];
      a0 = fmaf(uls[y*DIN + k],       w, a0);
      a1 = fmaf(uls[(y + 8)*DIN + k], w, a1);
    }
    t1s[y][c]     = fmaxf(a0, 0.f);
    t1s[y + 8][c] = fmaxf(a1, 0.f);
  }
  __syncthreads();

  {
    float z0 = b2[c], z1 = z0;
    for (int k = 0; k < 64; ++k) {
      float w = W2s[k*64 + c];
      z0 = fmaf(t1s[y][k],     w, z0);
      z1 = fmaf(t1s[y + 8][k], w, z1);
    }
    zout[(r0 + y)*64 + c]     = fmaxf(z0, 0.f);
    zout[(r0 + y + 8)*64 + c] = fmaxf(z1, 0.f);
  }
}

// ---------------------------------------------------------------------------
// head (stats sweep unrolled 4-deep like k_gin)
__global__ __launch_bounds__(512) void k_head(
    const float* __restrict__ z,
    const float* __restrict__ gg, const float* __restrict__ be,
    const float* __restrict__ l1w, const float* __restrict__ l1b,
    const float* __restrict__ l2w, const float* __restrict__ l2b,
    const float* __restrict__ nf,
    const float* __restrict__ epw1, const float* __restrict__ epb1,
    _Float16* __restrict__ Ah, _Float16* __restrict__ Bh) {
  __shared__ float W1s[4096];
  __shared__ float W2s[2048];
  __shared__ float Was[2048];
  __shared__ float Wbs[2048];
  __shared__ float scratch[4096];
  __shared__ float scl[64], sft[64];
  int tid = threadIdx.x, c = tid & 63, y = tid >> 6;
  for (int i = tid; i < 4096; i += 512) W1s[i] = l1w[i];
  for (int i = tid; i < 2048; i += 512) { W2s[i] = l2w[i]; Was[i] = epw1[i]; Wbs[i] = epw1[2048 + i]; }

  {
    int col4 = tid & 15, rseg = tid >> 4;  // RS = 32
    const f32x4* z4 = (const f32x4*)z;
    f32x4 s0 = {0.f,0.f,0.f,0.f}, s1 = s0, s2 = s0, s3 = s0;
    f32x4 q0 = s0, q1 = s0, q2 = s0, q3 = s0;
    for (int n = rseg; n < NN; n += 128) {
      f32x4 v0 = z4[n*16 + col4];
      f32x4 v1 = z4[(n + 32)*16 + col4];
      f32x4 v2 = z4[(n + 64)*16 + col4];
      f32x4 v3 = z4[(n + 96)*16 + col4];
      s0 += v0; q0 += v0*v0;
      s1 += v1; q1 += v1*v1;
      s2 += v2; q2 += v2*v2;
      s3 += v3; q3 += v3*v3;
    }
    f32x4 s4 = (s0 + s1) + (s2 + s3);
    f32x4 q4 = (q0 + q1) + (q2 + q3);
    float* red  = scratch;
    float* redq = scratch + 2048;
#pragma unroll
    for (int j = 0; j < 4; ++j) {
      red[rseg*64 + col4*4 + j]  = s4[j];
      redq[rseg*64 + col4*4 + j] = q4[j];
    }
    __syncthreads();
    if (tid < 64) {
      float S = 0.f, Q = 0.f;
      for (int r = 0; r < 32; ++r) { S += red[r*64 + tid]; Q += redq[r*64 + tid]; }
      float m  = S * (1.f/NN);
      float iv = rsqrtf(Q * (1.f/NN) - m*m + BN_EPS);
      float sc = iv * gg[tid];
      scl[tid] = sc;
      sft[tid] = be[tid] - m*sc;
    }
    __syncthreads();
  }

  float* t0 = scratch;
  float* t1 = scratch + 1024;
  float* t2 = scratch + 2048;
  int r0 = blockIdx.x*16;

  for (int rr = y; rr < 16; rr += 8)
    t0[rr*64 + c] = lrelu_f(z[(r0 + rr)*64 + c]*scl[c] + sft[c]);
  __syncthreads();
  {
    float a0 = l1b[c], a1 = a0;
    for (int k = 0; k < 64; ++k) {
      float w = W1s[k*64 + c];
      a0 = fmaf(t0[y*64 + k],       w, a0);
      a1 = fmaf(t0[(y + 8)*64 + k], w, a1);
    }
    t1[y*64 + c]       = lrelu_f(a0);
    t1[(y + 8)*64 + c] = lrelu_f(a1);
  }
  __syncthreads();
  if (c < 32) {
    float v0 = l2b[c], v1 = v0;
    for (int k = 0; k < 64; ++k) {
      float w = W2s[k*32 + c];
      v0 = fmaf(t1[y*64 + k],       w, v0);
      v1 = fmaf(t1[(y + 8)*64 + k], w, v1);
    }
    t2[y*32 + c]       = lrelu_f(v0) + nf[(r0 + y)*32 + c];
    t2[(y + 8)*32 + c] = lrelu_f(v1) + nf[(r0 + y + 8)*32 + c];
  }
  __syncthreads();
  {
    float av0 = epb1[c], av1 = av0;
    float bv0 = 0.f, bv1 = 0.f;
    for (int k = 0; k < 32; ++k) {
      float wa = Was[k*64 + c], wb = Wbs[k*64 + c];
      av0 = fmaf(t2[y*32 + k], wa, av0);       bv0 = fmaf(t2[y*32 + k], wb, bv0);
      av1 = fmaf(t2[(y + 8)*32 + k], wa, av1); bv1 = fmaf(t2[(y + 8)*32 + k], wb, bv1);
    }
    Ah[(r0 + y)*64 + c]     = (_Float16)av0;  Bh[(r0 + y)*64 + c]     = (_Float16)bv0;
    Ah[(r0 + y + 8)*64 + c] = (_Float16)av1;  Bh[(r0 + y + 8)*64 + c] = (_Float16)bv1;
  }
}

// ---------------------------------------------------------------------------
// Edge MLP, row-tiled + DUAL-GROUP interleave: each iteration runs two
// independent 16-edge chains (A/B) so MFMA/VALU of one hide the serial
// dependency latency of the other (round-8: both pipes <45% busy, 2 waves/SIMD
// cannot fill the serial chain gaps alone).
__global__ __launch_bounds__(256, 2) void k_edges_f16(
    const _Float16* __restrict__ Ah, const _Float16* __restrict__ Bh,
    const _Float16* __restrict__ Wf,
    const float* __restrict__ b2, const float* __restrict__ b3,
    const float* __restrict__ w4, const float* __restrict__ b4,
    float* __restrict__ out) {
  int tid = threadIdx.x, wid = tid >> 6, lane = tid & 63;
  int c = lane & 15, g = lane >> 4;

  // wave -> (s, chunk) band decode (uniform per wave)
  int w = blockIdx.x*4 + wid;
  int cum, kk, sbase;
  if (w < 1524) { cum = 0; kk = 12; sbase = 0; }
  else {
    cum = 1524; kk = 11; sbase = 127;
    while (kk > 1 && w >= cum + 128*kk) { cum += 128*kk; sbase += 128; --kk; }
  }
  int idx = w - cum;
  int q = idx / kk;
  int s = sbase + q;
  int t0 = s + 1 + ((idx - q*kk) << 7);

  // resident weights / biases
  const v8h* wp = (const v8h*)Wf;
  v8h wv2[8], wv3[8];
#pragma unroll
  for (int f = 0; f < 8; ++f) { wv2[f] = wp[f*64 + lane]; wv3[f] = wp[512 + f*64 + lane]; }

  f32x4 b2v[4], b3v[4], w4v[4];
  int g4 = g*4;
#pragma unroll
  for (int m = 0; m < 4; ++m)
#pragma unroll
    for (int r = 0; r < 4; ++r) {
      int f = 16*m + g4 + r;
      b2v[m][r] = b2[f]; b3v[m][r] = b3[f]; w4v[m][r] = w4[f];
    }
  float b4v = b4[0];

  V8H zu; zu.f4 = make_float4(0.f, 0.f, 0.f, 0.f);
  const v8h vzero = zu.v;

  // A[s] fragments: loop-invariant
  V8H a0, a1;
  a0.f4 = *(const float4*)(Ah + s*64 + g*8);
  a1.f4 = *(const float4*)(Ah + s*64 + 32 + g*8);

  // first B prefetch for both groups (clamped; overread lands in Wf: safe)
  int tla = min(t0 + c, NN - 1), tlb = min(t0 + 16 + c, NN - 1);
  V8H y0a, y1a, y0b, y1b;
  y0a.f4 = *(const float4*)(Bh + tla*64 + g*8);
  y1a.f4 = *(const float4*)(Bh + tla*64 + 32 + g*8);
  y0b.f4 = *(const float4*)(Bh + tlb*64 + g*8);
  y1b.f4 = *(const float4*)(Bh + tlb*64 + 32 + g*8);

  for (int it = 0; it < 4; ++it) {
    int tb0 = t0 + (it << 5);
    if (tb0 >= NN) break;              // uniform
    int ta = tb0 + c, tb = tb0 + 16 + c;

    V8H f0a, f1a, f0b, f1b;
    f0a.v = __builtin_elementwise_max(a0.v + y0a.v, vzero);
    f1a.v = __builtin_elementwise_max(a1.v + y1a.v, vzero);
    f0b.v = __builtin_elementwise_max(a0.v + y0b.v, vzero);
    f1b.v = __builtin_elementwise_max(a1.v + y1b.v, vzero);

    // prefetch next iteration's B rows for both groups
    int tna = min(tb0 + 32 + c, NN - 1), tnb = min(tb0 + 48 + c, NN - 1);
    y0a.f4 = *(const float4*)(Bh + tna*64 + g*8);
    y1a.f4 = *(const float4*)(Bh + tna*64 + 32 + g*8);
    y0b.f4 = *(const float4*)(Bh + tnb*64 + g*8);
    y1b.f4 = *(const float4*)(Bh + tnb*64 + 32 + g*8);

    // layer 2, both groups interleaved (bias as C-operand)
    __builtin_amdgcn_s_setprio(1);
    f32x4 acca[4], accb[4];
#pragma unroll
    for (int m = 0; m < 4; ++m) {
      acca[m] = __builtin_amdgcn_mfma_f32_16x16x32_f16(wv2[m], f0a.v, b2v[m], 0, 0, 0);
      accb[m] = __builtin_amdgcn_mfma_f32_16x16x32_f16(wv2[m], f0b.v, b2v[m], 0, 0, 0);
    }
#pragma unroll
    for (int m = 0; m < 4; ++m) {
      acca[m] = __builtin_amdgcn_mfma_f32_16x16x32_f16(wv2[4 + m], f1a.v, acca[m], 0, 0, 0);
      accb[m] = __builtin_amdgcn_mfma_f32_16x16x32_f16(wv2[4 + m], f1b.v, accb[m], 0, 0, 0);
    }
    __builtin_amdgcn_s_setprio(0);

    // relu (f32) + pack via v_cvt_pkrtz, both groups
    V8H p0a, p1a, p0b, p1b;
#pragma unroll
    for (int m = 0; m < 2; ++m) {
      p0a.h2[2*m]     = __builtin_amdgcn_cvt_pkrtz(fmaxf(acca[m][0], 0.f),   fmaxf(acca[m][1], 0.f));
      p0a.h2[2*m + 1] = __builtin_amdgcn_cvt_pkrtz(fmaxf(acca[m][2], 0.f),   fmaxf(acca[m][3], 0.f));
      p1a.h2[2*m]     = __builtin_amdgcn_cvt_pkrtz(fmaxf(acca[m+2][0], 0.f), fmaxf(acca[m+2][1], 0.f));
      p1a.h2[2*m + 1] = __builtin_amdgcn_cvt_pkrtz(fmaxf(acca[m+2][2], 0.f), fmaxf(acca[m+2][3], 0.f));
      p0b.h2[2*m]     = __builtin_amdgcn_cvt_pkrtz(fmaxf(accb[m][0], 0.f),   fmaxf(accb[m][1], 0.f));
      p0b.h2[2*m + 1] = __builtin_amdgcn_cvt_pkrtz(fmaxf(accb[m][2], 0.f),   fmaxf(accb[m][3], 0.f));
      p1b.h2[2*m]     = __builtin_amdgcn_cvt_pkrtz(fmaxf(accb[m+2][0], 0.f), fmaxf(accb[m+2][1], 0.f));
      p1b.h2[2*m + 1] = __builtin_amdgcn_cvt_pkrtz(fmaxf(accb[m+2][2], 0.f), fmaxf(accb[m+2][3], 0.f));
    }

    // layer 3, both groups interleaved
    __builtin_amdgcn_s_setprio(1);
    f32x4 ac3a[4], ac3b[4];
#pragma unroll
    for (int m = 0; m < 4; ++m) {
      ac3a[m] = __builtin_amdgcn_mfma_f32_16x16x32_f16(wv3[m], p0a.v, b3v[m], 0, 0, 0);
      ac3b[m] = __builtin_amdgcn_mfma_f32_16x16x32_f16(wv3[m], p0b.v, b3v[m], 0, 0, 0);
    }
#pragma unroll
    for (int m = 0; m < 4; ++m) {
      ac3a[m] = __builtin_amdgcn_mfma_f32_16x16x32_f16(wv3[4 + m], p1a.v, ac3a[m], 0, 0, 0);
      ac3b[m] = __builtin_amdgcn_mfma_f32_16x16x32_f16(wv3[4 + m], p1b.v, ac3b[m], 0, 0, 0);
    }
    __builtin_amdgcn_s_setprio(0);

    // layer 4 + reduce over g, both groups
    float pa = 0.f, pb = 0.f;
#pragma unroll
    for (int m = 0; m < 4; ++m)
#pragma unroll
      for (int r = 0; r < 4; ++r) {
        pa = fmaf(fmaxf(ac3a[m][r], 0.f), w4v[m][r], pa);
        pb = fmaf(fmaxf(ac3b[m][r], 0.f), w4v[m][r], pb);
      }
    pa += __shfl_xor(pa, 16, 64);
    pb += __shfl_xor(pb, 16, 64);
    pa += __shfl_xor(pa, 32, 64);
    pb += __shfl_xor(pb, 32, 64);
    float eza = __builtin_amdgcn_exp2f(-1.44269504f * (pa + b4v));
    float ezb = __builtin_amdgcn_exp2f(-1.44269504f * (pb + b4v));
    float proba = __builtin_amdgcn_rcpf(1.f + eza);
    float probb = __builtin_amdgcn_rcpf(1.f + ezb);
    if (lane < 16) {
      if (ta < NN) out[s*NN + ta] = proba;
      if (tb < NN) out[s*NN + tb] = probb;
    }
  }
}

// mirror: lower = upper^T, diag = 0. Triangular grid.
__global__ __launch_bounds__(256) void k_mirror(float* __restrict__ out) {
  __shared__ float tile[32][33];
  int k = blockIdx.x;
  int bi = (int)((sqrtf(8.f*k + 1.f) - 1.f)*0.5f);
  while (bi*(bi + 1)/2 > k) --bi;
  while ((bi + 1)*(bi + 2)/2 <= k) ++bi;
  int bj = k - bi*(bi + 1)/2;
  int i0 = bi*32, j0 = bj*32;
  int tx = threadIdx.x & 31, ty = threadIdx.x >> 5;
#pragma unroll
  for (int r = 0; r < 4; ++r)
    tile[ty + r*8][tx] = out[(j0 + ty + r*8)*NN + i0 + tx];
  __syncthreads();
#pragma unroll
  for (int r = 0; r < 4; ++r) {
    int row = ty + r*8;
    int i = i0 + row, j = j0 + tx;
    if (bi > bj)      out[i*NN + j] = tile[tx][row];
    else if (i > j)   out[i*NN + j] = tile[tx][row];
    else if (i == j)  out[i*NN + j] = 0.f;
  }
}

// ---------------------------------------------------------------------------
extern "C" void kernel_launch(void* const* d_in, const int* in_sizes, int n_in,
                              void* d_out, int out_size, void* d_ws, size_t ws_size,
                              hipStream_t stream) {
  const float* nf     = (const float*)d_in[1];
  const float* c1_eps = (const float*)d_in[2];
  const float* c1_w1  = (const float*)d_in[3];
  const float* c1_b1  = (const float*)d_in[4];
  const float* c1_w2  = (const float*)d_in[5];
  const float* c1_b2  = (const float*)d_in[6];
  const float* c1_g   = (const float*)d_in[7];
  const float* c1_be  = (const float*)d_in[8];
  const float* cv_eps = (const float*)d_in[9];
  const float* cv_w1  = (const float*)d_in[10];
  const float* cv_b1  = (const float*)d_in[11];
  const float* cv_w2  = (const float*)d_in[12];
  const float* cv_b2  = (const float*)d_in[13];
  const float* cv_g   = (const float*)d_in[14];
  const float* cv_be  = (const float*)d_in[15];
  const float* lin1_w = (const float*)d_in[16];
  const float* lin1_b = (const float*)d_in[17];
  const float* lin2_w = (const float*)d_in[18];
  const float* lin2_b = (const float*)d_in[19];
  const float* ep_w1  = (const float*)d_in[20];
  const float* ep_b1  = (const float*)d_in[21];
  const float* ep_w2  = (const float*)d_in[22];
  const float* ep_b2  = (const float*)d_in[23];
  const float* ep_w3  = (const float*)d_in[24];
  const float* ep_b3  = (const float*)d_in[25];
  const float* ep_w4  = (const float*)d_in[26];
  const float* ep_b4  = (const float*)d_in[27];

  float* ws = (float*)d_ws;
  float* zA    = ws;
  float* zB    = zA + NN*64;
  _Float16* Ah = (_Float16*)(zB + NN*64);
  _Float16* Bh = Ah + NN*64;
  _Float16* Wf = Bh + NN*64;   // absorbs Bh prefetch overread

  float* out = (float*)d_out;

  k_gin<32, true><<<112, 512, 0, stream>>>(nf, nullptr, nullptr, c1_eps,
      c1_w1, c1_b1, c1_w2, c1_b2, zA, ep_w2, ep_w3, Wf);

  k_gin<64, false><<<96, 512, 0, stream>>>(zA, c1_g, c1_be, cv_eps,
      cv_w1, cv_b1, cv_w2, cv_b2, zB, nullptr, nullptr, nullptr);

  k_gin<64, false><<<96, 512, 0, stream>>>(zB, cv_g, cv_be, cv_eps + 1,
      cv_w1 + HH*HH, cv_b1 + HH, cv_w2 + HH*HH, cv_b2 + HH, zA,
      nullptr, nullptr, nullptr);

  k_head<<<96, 512, 0, stream>>>(zA, cv_g + HH, cv_be + HH,
                                 lin1_w, lin1_b, lin2_w, lin2_b, nf,
                                 ep_w1, ep_b1, Ah, Bh);

  k_edges_f16<<<EBLK, 256, 0, stream>>>(Ah, Bh, Wf, ep_b2, ep_b3, ep_w4, ep_b4, out);

  k_mirror<<<1176, 256, 0, stream>>>(out);
}

// Round 10
// 88.998 us; speedup vs baseline: 3.5884x; 1.0614x over previous
//
#include <hip/hip_runtime.h>
#include <math.h>

#define NN 1536
#define FF 32
#define HH 64
#define EE (NN*(NN-1)/2)
#define EBLK 2493          // 2493 blocks * 4 waves = 9972 = exact padded chunk count
#define BN_EPS 1e-5f
#define SLOPE 0.01f

typedef _Float16 v8h  __attribute__((ext_vector_type(8)));
typedef __fp16   v2hf __attribute__((ext_vector_type(2)));
typedef float    f32x4 __attribute__((ext_vector_type(4)));

union V8H { v8h v; v2hf h2[4]; float4 f4; };

__device__ __forceinline__ float lrelu_f(float v){ return v >= 0.f ? v : SLOPE*v; }
__device__ __forceinline__ f32x4 lrelu4(f32x4 v) {
  f32x4 r;
#pragma unroll
  for (int j = 0; j < 4; ++j) r[j] = v[j] >= 0.f ? v[j] : SLOPE*v[j];
  return r;
}

// ---------------------------------------------------------------------------
// Fused GIN layer (r9 structure: no cross-block comm, redundant deterministic
// stats, multi-accumulator sweeps).
template<int DIN, bool FIRST>
__global__ __launch_bounds__(512) void k_gin(
    const float* __restrict__ zin,
    const float* __restrict__ gg, const float* __restrict__ be,
    const float* __restrict__ eps_p,
    const float* __restrict__ W1, const float* __restrict__ b1,
    const float* __restrict__ W2, const float* __restrict__ b2,
    float* __restrict__ zout,
    const float* __restrict__ pw2, const float* __restrict__ pw3,
    _Float16* __restrict__ pwf) {
  int bid = blockIdx.x, tid = threadIdx.x;
  if (FIRST && bid >= 96) {
    int i = (bid - 96)*512 + tid;
    if (i < 8192) {
      int mat = i >> 12, r = i & 4095;
      int k = r >> 6, cout = r & 63;
      int m = cout >> 4, cc = cout & 15;
      int q, g, b;
      if (mat == 0) { q = k >> 5; g = (k >> 3) & 3; b = k & 7; }
      else { int mF = k >> 4; g = (k >> 2) & 3; int rr = k & 3; q = mF >> 1; b = ((mF & 1) << 2) | rr; }
      const float* W = mat ? pw3 : pw2;
      pwf[mat*4096 + ((q*4 + m)*64 + (g*16 + cc))*8 + b] = (_Float16)W[r];
    }
    return;
  }

  __shared__ float W1s[DIN*64];
  __shared__ float W2s[4096];
  __shared__ float red[2048];
  __shared__ float redq[2048];
  __shared__ float scl[64], sft[64], pf[64];
  __shared__ float hh[16][64];
  __shared__ float uls[16*64];
  __shared__ float t1s[16][64];

  int c = tid & 63, y = tid >> 6;
  for (int i = tid; i < DIN*64; i += 512) W1s[i] = W1[i];
  for (int i = tid; i < 4096; i += 512)   W2s[i] = W2[i];

  constexpr int C4 = DIN/4;
  constexpr int RS = 512/C4;
  int col4 = tid % C4, rseg = tid / C4;
  const f32x4* z4 = (const f32x4*)zin;
  int r0 = bid*16;

  if (!FIRST) {
    f32x4 s0 = {0.f,0.f,0.f,0.f}, s1 = s0, s2 = s0, s3 = s0;
    f32x4 q0 = s0, q1 = s0, q2 = s0, q3 = s0;
    for (int n = rseg; n < NN; n += 4*RS) {
      f32x4 v0 = z4[n*C4 + col4];
      f32x4 v1 = z4[(n + RS)*C4 + col4];
      f32x4 v2 = z4[(n + 2*RS)*C4 + col4];
      f32x4 v3 = z4[(n + 3*RS)*C4 + col4];
      s0 += v0; q0 += v0*v0;
      s1 += v1; q1 += v1*v1;
      s2 += v2; q2 += v2*v2;
      s3 += v3; q3 += v3*v3;
    }
    f32x4 s4 = (s0 + s1) + (s2 + s3);
    f32x4 q4 = (q0 + q1) + (q2 + q3);
#pragma unroll
    for (int j = 0; j < 4; ++j) {
      red[rseg*DIN + col4*4 + j]  = s4[j];
      redq[rseg*DIN + col4*4 + j] = q4[j];
    }
    __syncthreads();
    if (tid < DIN) {
      float S = 0.f, Q = 0.f;
      for (int r = 0; r < RS; ++r) { S += red[r*DIN + tid]; Q += redq[r*DIN + tid]; }
      float m  = S * (1.f/NN);
      float iv = rsqrtf(Q * (1.f/NN) - m*m + BN_EPS);
      float sc = iv * gg[tid];
      scl[tid] = sc;
      sft[tid] = be[tid] - m*sc;
    }
    __syncthreads();
  }

  {
    f32x4 p0 = {0.f,0.f,0.f,0.f}, p1 = p0;
    f32x4 sc4, sh4;
    if (!FIRST) {
#pragma unroll
      for (int j = 0; j < 4; ++j) { sc4[j] = scl[col4*4 + j]; sh4[j] = sft[col4*4 + j]; }
    }
    int n = rseg;
    for (; n + RS < r0; n += 2*RS) {
      f32x4 va = z4[n*C4 + col4];
      f32x4 vb = z4[(n + RS)*C4 + col4];
      if (!FIRST) { va = lrelu4(va*sc4 + sh4); vb = lrelu4(vb*sc4 + sh4); }
      p0 += va; p1 += vb;
    }
    for (; n < r0; n += RS) {
      f32x4 va = z4[n*C4 + col4];
      if (!FIRST) va = lrelu4(va*sc4 + sh4);
      p0 += va;
    }
    p0 += p1;
#pragma unroll
    for (int j = 0; j < 4; ++j) red[rseg*DIN + col4*4 + j] = p0[j];
    __syncthreads();
    if (tid < DIN) {
      float S = 0.f;
      for (int r = 0; r < RS; ++r) S += red[r*DIN + tid];
      pf[tid] = S;
    }
    __syncthreads();
  }

  float e1 = 1.f + eps_p[0];
  if (c < DIN) {
    for (int rr = y; rr < 16; rr += 8) {
      float v = zin[(r0 + rr)*DIN + c];
      hh[rr][c] = FIRST ? v : lrelu_f(v*scl[c] + sft[c]);
    }
  }
  __syncthreads();
  if (c < DIN) {
    for (int rr = y; rr < 16; rr += 8) {
      float run = pf[c];
      for (int r2 = 0; r2 < rr; ++r2) run += hh[r2][c];
      uls[rr*DIN + c] = e1*hh[rr][c] + run;
    }
  }
  __syncthreads();

  {
    float a0 = b1[c], a1 = a0;
    for (int k = 0; k < DIN; ++k) {
      float w = W1s[k*64 + c];
      a0 = fmaf(uls[y*DIN + k],       w, a0);
      a1 = fmaf(uls[(y + 8)*DIN + k], w, a1);
    }
    t1s[y][c]     = fmaxf(a0, 0.f);
    t1s[y + 8][c] = fmaxf(a1, 0.f);
  }
  __syncthreads();

  {
    float z0 = b2[c], z1 = z0;
    for (int k = 0; k < 64; ++k) {
      float w = W2s[k*64 + c];
      z0 = fmaf(t1s[y][k],     w, z0);
      z1 = fmaf(t1s[y + 8][k], w, z1);
    }
    zout[(r0 + y)*64 + c]     = fmaxf(z0, 0.f);
    zout[(r0 + y + 8)*64 + c] = fmaxf(z1, 0.f);
  }
}

// ---------------------------------------------------------------------------
// head (r9 structure)
__global__ __launch_bounds__(512) void k_head(
    const float* __restrict__ z,
    const float* __restrict__ gg, const float* __restrict__ be,
    const float* __restrict__ l1w, const float* __restrict__ l1b,
    const float* __restrict__ l2w, const float* __restrict__ l2b,
    const float* __restrict__ nf,
    const float* __restrict__ epw1, const float* __restrict__ epb1,
    _Float16* __restrict__ Ah, _Float16* __restrict__ Bh) {
  __shared__ float W1s[4096];
  __shared__ float W2s[2048];
  __shared__ float Was[2048];
  __shared__ float Wbs[2048];
  __shared__ float scratch[4096];
  __shared__ float scl[64], sft[64];
  int tid = threadIdx.x, c = tid & 63, y = tid >> 6;
  for (int i = tid; i < 4096; i += 512) W1s[i] = l1w[i];
  for (int i = tid; i < 2048; i += 512) { W2s[i] = l2w[i]; Was[i] = epw1[i]; Wbs[i] = epw1[2048 + i]; }

  {
    int col4 = tid & 15, rseg = tid >> 4;  // RS = 32
    const f32x4* z4 = (const f32x4*)z;
    f32x4 s0 = {0.f,0.f,0.f,0.f}, s1 = s0, s2 = s0, s3 = s0;
    f32x4 q0 = s0, q1 = s0, q2 = s0, q3 = s0;
    for (int n = rseg; n < NN; n += 128) {
      f32x4 v0 = z4[n*16 + col4];
      f32x4 v1 = z4[(n + 32)*16 + col4];
      f32x4 v2 = z4[(n + 64)*16 + col4];
      f32x4 v3 = z4[(n + 96)*16 + col4];
      s0 += v0; q0 += v0*v0;
      s1 += v1; q1 += v1*v1;
      s2 += v2; q2 += v2*v2;
      s3 += v3; q3 += v3*v3;
    }
    f32x4 s4 = (s0 + s1) + (s2 + s3);
    f32x4 q4 = (q0 + q1) + (q2 + q3);
    float* red  = scratch;
    float* redq = scratch + 2048;
#pragma unroll
    for (int j = 0; j < 4; ++j) {
      red[rseg*64 + col4*4 + j]  = s4[j];
      redq[rseg*64 + col4*4 + j] = q4[j];
    }
    __syncthreads();
    if (tid < 64) {
      float S = 0.f, Q = 0.f;
      for (int r = 0; r < 32; ++r) { S += red[r*64 + tid]; Q += redq[r*64 + tid]; }
      float m  = S * (1.f/NN);
      float iv = rsqrtf(Q * (1.f/NN) - m*m + BN_EPS);
      float sc = iv * gg[tid];
      scl[tid] = sc;
      sft[tid] = be[tid] - m*sc;
    }
    __syncthreads();
  }

  float* t0 = scratch;
  float* t1 = scratch + 1024;
  float* t2 = scratch + 2048;
  int r0 = blockIdx.x*16;

  for (int rr = y; rr < 16; rr += 8)
    t0[rr*64 + c] = lrelu_f(z[(r0 + rr)*64 + c]*scl[c] + sft[c]);
  __syncthreads();
  {
    float a0 = l1b[c], a1 = a0;
    for (int k = 0; k < 64; ++k) {
      float w = W1s[k*64 + c];
      a0 = fmaf(t0[y*64 + k],       w, a0);
      a1 = fmaf(t0[(y + 8)*64 + k], w, a1);
    }
    t1[y*64 + c]       = lrelu_f(a0);
    t1[(y + 8)*64 + c] = lrelu_f(a1);
  }
  __syncthreads();
  if (c < 32) {
    float v0 = l2b[c], v1 = v0;
    for (int k = 0; k < 64; ++k) {
      float w = W2s[k*32 + c];
      v0 = fmaf(t1[y*64 + k],       w, v0);
      v1 = fmaf(t1[(y + 8)*64 + k], w, v1);
    }
    t2[y*32 + c]       = lrelu_f(v0) + nf[(r0 + y)*32 + c];
    t2[(y + 8)*32 + c] = lrelu_f(v1) + nf[(r0 + y + 8)*32 + c];
  }
  __syncthreads();
  {
    float av0 = epb1[c], av1 = av0;
    float bv0 = 0.f, bv1 = 0.f;
    for (int k = 0; k < 32; ++k) {
      float wa = Was[k*64 + c], wb = Wbs[k*64 + c];
      av0 = fmaf(t2[y*32 + k], wa, av0);       bv0 = fmaf(t2[y*32 + k], wb, bv0);
      av1 = fmaf(t2[(y + 8)*32 + k], wa, av1); bv1 = fmaf(t2[(y + 8)*32 + k], wb, bv1);
    }
    Ah[(r0 + y)*64 + c]     = (_Float16)av0;  Bh[(r0 + y)*64 + c]     = (_Float16)bv0;
    Ah[(r0 + y + 8)*64 + c] = (_Float16)av1;  Bh[(r0 + y + 8)*64 + c] = (_Float16)bv1;
  }
}

// ---------------------------------------------------------------------------
// Edge MLP, row-tiled single-group, register-dieted for 3 waves/SIMD:
// - launch_bounds(256,3): rounds 4-9 sat at 2 waves/SIMD (256-reg cap used
//   in full); extra resident wave is the latency-hiding lever.
// - w4 as packed f16 + v_dot2 layer-4; cvt_pkrtz->pk_max pack; no clamps
//   (Bh overread <4KB lands in the Wf region, safe by ws layout).
__global__ __launch_bounds__(256, 3) void k_edges_f16(
    const _Float16* __restrict__ Ah, const _Float16* __restrict__ Bh,
    const _Float16* __restrict__ Wf,
    const float* __restrict__ b2, const float* __restrict__ b3,
    const float* __restrict__ w4, const float* __restrict__ b4,
    float* __restrict__ out) {
  int tid = threadIdx.x, wid = tid >> 6, lane = tid & 63;
  int c = lane & 15, g = lane >> 4;

  // wave -> (s, chunk) band decode (uniform per wave)
  int w = blockIdx.x*4 + wid;
  int cum, kk, sbase;
  if (w < 1524) { cum = 0; kk = 12; sbase = 0; }
  else {
    cum = 1524; kk = 11; sbase = 127;
    while (kk > 1 && w >= cum + 128*kk) { cum += 128*kk; sbase += 128; --kk; }
  }
  int idx = w - cum;
  int q = idx / kk;
  int s = sbase + q;
  int t0 = s + 1 + ((idx - q*kk) << 7);

  // resident weights
  const v8h* wp = (const v8h*)Wf;
  v8h wv2[8], wv3[8];
#pragma unroll
  for (int f = 0; f < 8; ++f) { wv2[f] = wp[f*64 + lane]; wv3[f] = wp[512 + f*64 + lane]; }

  // b2,b3 as f32x4 C-operands; w4 packed f16 for v_dot2
  f32x4 b2v[4], b3v[4];
  v2hf w4h[8];
  int g4 = g*4;
#pragma unroll
  for (int m = 0; m < 4; ++m) {
#pragma unroll
    for (int r = 0; r < 4; ++r) {
      int f = 16*m + g4 + r;
      b2v[m][r] = b2[f]; b3v[m][r] = b3[f];
    }
    v2hf wa = { (__fp16)w4[16*m + g4],     (__fp16)w4[16*m + g4 + 1] };
    v2hf wb = { (__fp16)w4[16*m + g4 + 2], (__fp16)w4[16*m + g4 + 3] };
    w4h[2*m] = wa; w4h[2*m + 1] = wb;
  }
  float b4v = b4[0];

  V8H zu; zu.f4 = make_float4(0.f, 0.f, 0.f, 0.f);
  const v8h vzero = zu.v;
  const v2hf z2 = { (__fp16)0.f, (__fp16)0.f };

  // A[s] fragments: loop-invariant
  V8H a0, a1;
  a0.f4 = *(const float4*)(Ah + s*64 + g*8);
  a1.f4 = *(const float4*)(Ah + s*64 + 32 + g*8);

  // first B prefetch (no clamp: overread lands in Wf region)
  int tl = t0 + c;
  V8H y0, y1;
  y0.f4 = *(const float4*)(Bh + tl*64 + g*8);
  y1.f4 = *(const float4*)(Bh + tl*64 + 32 + g*8);

  for (int it = 0; it < 8; ++it) {
    int tb = t0 + (it << 4);
    if (tb >= NN) break;               // uniform
    int t = tb + c;

    V8H f0, f1;
    f0.v = __builtin_elementwise_max(a0.v + y0.v, vzero);
    f1.v = __builtin_elementwise_max(a1.v + y1.v, vzero);

    // prefetch next group's B rows
    int tn = tb + 16 + c;
    y0.f4 = *(const float4*)(Bh + tn*64 + g*8);
    y1.f4 = *(const float4*)(Bh + tn*64 + 32 + g*8);

    // layer 2 (bias as C-operand; D != C, no copy)
    __builtin_amdgcn_s_setprio(1);
    f32x4 acc[4];
#pragma unroll
    for (int m = 0; m < 4; ++m)
      acc[m] = __builtin_amdgcn_mfma_f32_16x16x32_f16(wv2[m],     f0.v, b2v[m], 0, 0, 0);
#pragma unroll
    for (int m = 0; m < 4; ++m)
      acc[m] = __builtin_amdgcn_mfma_f32_16x16x32_f16(wv2[4 + m], f1.v, acc[m], 0, 0, 0);
    __builtin_amdgcn_s_setprio(0);

    // relu via packed f16 max after cvt_pkrtz
    V8H p0, p1;
#pragma unroll
    for (int m = 0; m < 2; ++m) {
      p0.h2[2*m]     = __builtin_elementwise_max(__builtin_amdgcn_cvt_pkrtz(acc[m][0],   acc[m][1]),   z2);
      p0.h2[2*m + 1] = __builtin_elementwise_max(__builtin_amdgcn_cvt_pkrtz(acc[m][2],   acc[m][3]),   z2);
      p1.h2[2*m]     = __builtin_elementwise_max(__builtin_amdgcn_cvt_pkrtz(acc[m+2][0], acc[m+2][1]), z2);
      p1.h2[2*m + 1] = __builtin_elementwise_max(__builtin_amdgcn_cvt_pkrtz(acc[m+2][2], acc[m+2][3]), z2);
    }

    // layer 3 (b3 as C-operand)
    __builtin_amdgcn_s_setprio(1);
    f32x4 acc3[4];
#pragma unroll
    for (int m = 0; m < 4; ++m)
      acc3[m] = __builtin_amdgcn_mfma_f32_16x16x32_f16(wv3[m],     p0.v, b3v[m], 0, 0, 0);
#pragma unroll
    for (int m = 0; m < 4; ++m)
      acc3[m] = __builtin_amdgcn_mfma_f32_16x16x32_f16(wv3[4 + m], p1.v, acc3[m], 0, 0, 0);
    __builtin_amdgcn_s_setprio(0);

    // layer 4: relu -> f16 pack -> v_dot2 with packed w4
    float p = 0.f;
#pragma unroll
    for (int m = 0; m < 4; ++m) {
      v2hf l0 = __builtin_elementwise_max(
          __builtin_amdgcn_cvt_pkrtz(acc3[m][0], acc3[m][1]), z2);
      v2hf l1 = __builtin_elementwise_max(
          __builtin_amdgcn_cvt_pkrtz(acc3[m][2], acc3[m][3]), z2);
      p = __builtin_amdgcn_fdot2(l0, w4h[2*m],     p, false);
      p = __builtin_amdgcn_fdot2(l1, w4h[2*m + 1], p, false);
    }
    p += __shfl_xor(p, 16, 64);
    p += __shfl_xor(p, 32, 64);
    float ez = __builtin_amdgcn_exp2f(-1.44269504f * (p + b4v));
    float prob = __builtin_amdgcn_rcpf(1.f + ez);
    if (lane < 16 && t < NN) out[s*NN + t] = prob;   // upper triangle, coalesced
  }
}

// mirror: lower = upper^T, diag = 0. Triangular grid.
__global__ __launch_bounds__(256) void k_mirror(float* __restrict__ out) {
  __shared__ float tile[32][33];
  int k = blockIdx.x;
  int bi = (int)((sqrtf(8.f*k + 1.f) - 1.f)*0.5f);
  while (bi*(bi + 1)/2 > k) --bi;
  while ((bi + 1)*(bi + 2)/2 <= k) ++bi;
  int bj = k - bi*(bi + 1)/2;
  int i0 = bi*32, j0 = bj*32;
  int tx = threadIdx.x & 31, ty = threadIdx.x >> 5;
#pragma unroll
  for (int r = 0; r < 4; ++r)
    tile[ty + r*8][tx] = out[(j0 + ty + r*8)*NN + i0 + tx];
  __syncthreads();
#pragma unroll
  for (int r = 0; r < 4; ++r) {
    int row = ty + r*8;
    int i = i0 + row, j = j0 + tx;
    if (bi > bj)      out[i*NN + j] = tile[tx][row];
    else if (i > j)   out[i*NN + j] = tile[tx][row];
    else if (i == j)  out[i*NN + j] = 0.f;
  }
}

// ---------------------------------------------------------------------------
extern "C" void kernel_launch(void* const* d_in, const int* in_sizes, int n_in,
                              void* d_out, int out_size, void* d_ws, size_t ws_size,
                              hipStream_t stream) {
  const float* nf     = (const float*)d_in[1];
  const float* c1_eps = (const float*)d_in[2];
  const float* c1_w1  = (const float*)d_in[3];
  const float* c1_b1  = (const float*)d_in[4];
  const float* c1_w2  = (const float*)d_in[5];
  const float* c1_b2  = (const float*)d_in[6];
  const float* c1_g   = (const float*)d_in[7];
  const float* c1_be  = (const float*)d_in[8];
  const float* cv_eps = (const float*)d_in[9];
  const float* cv_w1  = (const float*)d_in[10];
  const float* cv_b1  = (const float*)d_in[11];
  const float* cv_w2  = (const float*)d_in[12];
  const float* cv_b2  = (const float*)d_in[13];
  const float* cv_g   = (const float*)d_in[14];
  const float* cv_be  = (const float*)d_in[15];
  const float* lin1_w = (const float*)d_in[16];
  const float* lin1_b = (const float*)d_in[17];
  const float* lin2_w = (const float*)d_in[18];
  const float* lin2_b = (const float*)d_in[19];
  const float* ep_w1  = (const float*)d_in[20];
  const float* ep_b1  = (const float*)d_in[21];
  const float* ep_w2  = (const float*)d_in[22];
  const float* ep_b2  = (const float*)d_in[23];
  const float* ep_w3  = (const float*)d_in[24];
  const float* ep_b3  = (const float*)d_in[25];
  const float* ep_w4  = (const float*)d_in[26];
  const float* ep_b4  = (const float*)d_in[27];

  float* ws = (float*)d_ws;
  float* zA    = ws;
  float* zB    = zA + NN*64;
  _Float16* Ah = (_Float16*)(zB + NN*64);
  _Float16* Bh = Ah + NN*64;
  _Float16* Wf = Bh + NN*64;   // absorbs Bh prefetch overread (<4KB, Wf=16KB)

  float* out = (float*)d_out;

  k_gin<32, true><<<112, 512, 0, stream>>>(nf, nullptr, nullptr, c1_eps,
      c1_w1, c1_b1, c1_w2, c1_b2, zA, ep_w2, ep_w3, Wf);

  k_gin<64, false><<<96, 512, 0, stream>>>(zA, c1_g, c1_be, cv_eps,
      cv_w1, cv_b1, cv_w2, cv_b2, zB, nullptr, nullptr, nullptr);

  k_gin<64, false><<<96, 512, 0, stream>>>(zB, cv_g, cv_be, cv_eps + 1,
      cv_w1 + HH*HH, cv_b1 + HH, cv_w2 + HH*HH, cv_b2 + HH, zA,
      nullptr, nullptr, nullptr);

  k_head<<<96, 512, 0, stream>>>(zA, cv_g + HH, cv_be + HH,
                                 lin1_w, lin1_b, lin2_w, lin2_b, nf,
                                 ep_w1, ep_b1, Ah, Bh);

  k_edges_f16<<<EBLK, 256, 0, stream>>>(Ah, Bh, Wf, ep_b2, ep_b3, ep_w4, ep_b4, out);

  k_mirror<<<1176, 256, 0, stream>>>(out);
}

// Round 11
// 87.042 us; speedup vs baseline: 3.6691x; 1.0225x over previous
//
#include <hip/hip_runtime.h>
#include <math.h>

#define NN 1536
#define FF 32
#define HH 64
#define EE (NN*(NN-1)/2)
#define EBLK 2493          // 2493 blocks * 4 waves = 9972 = exact padded chunk count
#define BN_EPS 1e-5f
#define SLOPE 0.01f

typedef _Float16 v8h  __attribute__((ext_vector_type(8)));
typedef __fp16   v2hf __attribute__((ext_vector_type(2)));
typedef float    f32x4 __attribute__((ext_vector_type(4)));

union V8H { v8h v; v2hf h2[4]; float4 f4; };

__device__ __forceinline__ float lrelu_f(float v){ return v >= 0.f ? v : SLOPE*v; }
__device__ __forceinline__ f32x4 lrelu4(f32x4 v) {
  f32x4 r;
#pragma unroll
  for (int j = 0; j < 4; ++j) r[j] = v[j] >= 0.f ? v[j] : SLOPE*v[j];
  return r;
}

// ---------------------------------------------------------------------------
// Fused GIN layer (no cross-block comm, redundant deterministic stats,
// multi-accumulator sweeps; prefix now 4-deep unrolled).
template<int DIN, bool FIRST>
__global__ __launch_bounds__(512) void k_gin(
    const float* __restrict__ zin,
    const float* __restrict__ gg, const float* __restrict__ be,
    const float* __restrict__ eps_p,
    const float* __restrict__ W1, const float* __restrict__ b1,
    const float* __restrict__ W2, const float* __restrict__ b2,
    float* __restrict__ zout,
    const float* __restrict__ pw2, const float* __restrict__ pw3,
    _Float16* __restrict__ pwf) {
  int bid = blockIdx.x, tid = threadIdx.x;
  if (FIRST && bid >= 96) {
    int i = (bid - 96)*512 + tid;
    if (i < 8192) {
      int mat = i >> 12, r = i & 4095;
      int k = r >> 6, cout = r & 63;
      int m = cout >> 4, cc = cout & 15;
      int q, g, b;
      if (mat == 0) { q = k >> 5; g = (k >> 3) & 3; b = k & 7; }
      else { int mF = k >> 4; g = (k >> 2) & 3; int rr = k & 3; q = mF >> 1; b = ((mF & 1) << 2) | rr; }
      const float* W = mat ? pw3 : pw2;
      pwf[mat*4096 + ((q*4 + m)*64 + (g*16 + cc))*8 + b] = (_Float16)W[r];
    }
    return;
  }

  __shared__ float W1s[DIN*64];
  __shared__ float W2s[4096];
  __shared__ float red[2048];
  __shared__ float redq[2048];
  __shared__ float scl[64], sft[64], pf[64];
  __shared__ float hh[16][64];
  __shared__ float uls[16*64];
  __shared__ float t1s[16][64];

  int c = tid & 63, y = tid >> 6;
  for (int i = tid; i < DIN*64; i += 512) W1s[i] = W1[i];
  for (int i = tid; i < 4096; i += 512)   W2s[i] = W2[i];

  constexpr int C4 = DIN/4;
  constexpr int RS = 512/C4;
  int col4 = tid % C4, rseg = tid / C4;
  const f32x4* z4 = (const f32x4*)zin;
  int r0 = bid*16;

  if (!FIRST) {
    f32x4 s0 = {0.f,0.f,0.f,0.f}, s1 = s0, s2 = s0, s3 = s0;
    f32x4 q0 = s0, q1 = s0, q2 = s0, q3 = s0;
    for (int n = rseg; n < NN; n += 4*RS) {
      f32x4 v0 = z4[n*C4 + col4];
      f32x4 v1 = z4[(n + RS)*C4 + col4];
      f32x4 v2 = z4[(n + 2*RS)*C4 + col4];
      f32x4 v3 = z4[(n + 3*RS)*C4 + col4];
      s0 += v0; q0 += v0*v0;
      s1 += v1; q1 += v1*v1;
      s2 += v2; q2 += v2*v2;
      s3 += v3; q3 += v3*v3;
    }
    f32x4 s4 = (s0 + s1) + (s2 + s3);
    f32x4 q4 = (q0 + q1) + (q2 + q3);
#pragma unroll
    for (int j = 0; j < 4; ++j) {
      red[rseg*DIN + col4*4 + j]  = s4[j];
      redq[rseg*DIN + col4*4 + j] = q4[j];
    }
    __syncthreads();
    if (tid < DIN) {
      float S = 0.f, Q = 0.f;
      for (int r = 0; r < RS; ++r) { S += red[r*DIN + tid]; Q += redq[r*DIN + tid]; }
      float m  = S * (1.f/NN);
      float iv = rsqrtf(Q * (1.f/NN) - m*m + BN_EPS);
      float sc = iv * gg[tid];
      scl[tid] = sc;
      sft[tid] = be[tid] - m*sc;
    }
    __syncthreads();
  }

  {
    // prefix sweep, 4 loads in flight
    f32x4 p0 = {0.f,0.f,0.f,0.f}, p1 = p0, p2 = p0, p3 = p0;
    f32x4 sc4, sh4;
    if (!FIRST) {
#pragma unroll
      for (int j = 0; j < 4; ++j) { sc4[j] = scl[col4*4 + j]; sh4[j] = sft[col4*4 + j]; }
    }
    int n = rseg;
    for (; n + 3*RS < r0; n += 4*RS) {
      f32x4 va = z4[n*C4 + col4];
      f32x4 vb = z4[(n + RS)*C4 + col4];
      f32x4 vc = z4[(n + 2*RS)*C4 + col4];
      f32x4 vd = z4[(n + 3*RS)*C4 + col4];
      if (!FIRST) {
        va = lrelu4(va*sc4 + sh4); vb = lrelu4(vb*sc4 + sh4);
        vc = lrelu4(vc*sc4 + sh4); vd = lrelu4(vd*sc4 + sh4);
      }
      p0 += va; p1 += vb; p2 += vc; p3 += vd;
    }
    for (; n < r0; n += RS) {
      f32x4 va = z4[n*C4 + col4];
      if (!FIRST) va = lrelu4(va*sc4 + sh4);
      p0 += va;
    }
    p0 = (p0 + p1) + (p2 + p3);
#pragma unroll
    for (int j = 0; j < 4; ++j) red[rseg*DIN + col4*4 + j] = p0[j];
    __syncthreads();
    if (tid < DIN) {
      float S = 0.f;
      for (int r = 0; r < RS; ++r) S += red[r*DIN + tid];
      pf[tid] = S;
    }
    __syncthreads();
  }

  float e1 = 1.f + eps_p[0];
  if (c < DIN) {
    for (int rr = y; rr < 16; rr += 8) {
      float v = zin[(r0 + rr)*DIN + c];
      hh[rr][c] = FIRST ? v : lrelu_f(v*scl[c] + sft[c]);
    }
  }
  __syncthreads();
  if (c < DIN) {
    for (int rr = y; rr < 16; rr += 8) {
      float run = pf[c];
      for (int r2 = 0; r2 < rr; ++r2) run += hh[r2][c];
      uls[rr*DIN + c] = e1*hh[rr][c] + run;
    }
  }
  __syncthreads();

  {
    float a0 = b1[c], a1 = a0;
    for (int k = 0; k < DIN; ++k) {
      float w = W1s[k*64 + c];
      a0 = fmaf(uls[y*DIN + k],       w, a0);
      a1 = fmaf(uls[(y + 8)*DIN + k], w, a1);
    }
    t1s[y][c]     = fmaxf(a0, 0.f);
    t1s[y + 8][c] = fmaxf(a1, 0.f);
  }
  __syncthreads();

  {
    float z0 = b2[c], z1 = z0;
    for (int k = 0; k < 64; ++k) {
      float w = W2s[k*64 + c];
      z0 = fmaf(t1s[y][k],     w, z0);
      z1 = fmaf(t1s[y + 8][k], w, z1);
    }
    zout[(r0 + y)*64 + c]     = fmaxf(z0, 0.f);
    zout[(r0 + y + 8)*64 + c] = fmaxf(z1, 0.f);
  }
}

// ---------------------------------------------------------------------------
// head (unchanged)
__global__ __launch_bounds__(512) void k_head(
    const float* __restrict__ z,
    const float* __restrict__ gg, const float* __restrict__ be,
    const float* __restrict__ l1w, const float* __restrict__ l1b,
    const float* __restrict__ l2w, const float* __restrict__ l2b,
    const float* __restrict__ nf,
    const float* __restrict__ epw1, const float* __restrict__ epb1,
    _Float16* __restrict__ Ah, _Float16* __restrict__ Bh) {
  __shared__ float W1s[4096];
  __shared__ float W2s[2048];
  __shared__ float Was[2048];
  __shared__ float Wbs[2048];
  __shared__ float scratch[4096];
  __shared__ float scl[64], sft[64];
  int tid = threadIdx.x, c = tid & 63, y = tid >> 6;
  for (int i = tid; i < 4096; i += 512) W1s[i] = l1w[i];
  for (int i = tid; i < 2048; i += 512) { W2s[i] = l2w[i]; Was[i] = epw1[i]; Wbs[i] = epw1[2048 + i]; }

  {
    int col4 = tid & 15, rseg = tid >> 4;  // RS = 32
    const f32x4* z4 = (const f32x4*)z;
    f32x4 s0 = {0.f,0.f,0.f,0.f}, s1 = s0, s2 = s0, s3 = s0;
    f32x4 q0 = s0, q1 = s0, q2 = s0, q3 = s0;
    for (int n = rseg; n < NN; n += 128) {
      f32x4 v0 = z4[n*16 + col4];
      f32x4 v1 = z4[(n + 32)*16 + col4];
      f32x4 v2 = z4[(n + 64)*16 + col4];
      f32x4 v3 = z4[(n + 96)*16 + col4];
      s0 += v0; q0 += v0*v0;
      s1 += v1; q1 += v1*v1;
      s2 += v2; q2 += v2*v2;
      s3 += v3; q3 += v3*v3;
    }
    f32x4 s4 = (s0 + s1) + (s2 + s3);
    f32x4 q4 = (q0 + q1) + (q2 + q3);
    float* red  = scratch;
    float* redq = scratch + 2048;
#pragma unroll
    for (int j = 0; j < 4; ++j) {
      red[rseg*64 + col4*4 + j]  = s4[j];
      redq[rseg*64 + col4*4 + j] = q4[j];
    }
    __syncthreads();
    if (tid < 64) {
      float S = 0.f, Q = 0.f;
      for (int r = 0; r < 32; ++r) { S += red[r*64 + tid]; Q += redq[r*64 + tid]; }
      float m  = S * (1.f/NN);
      float iv = rsqrtf(Q * (1.f/NN) - m*m + BN_EPS);
      float sc = iv * gg[tid];
      scl[tid] = sc;
      sft[tid] = be[tid] - m*sc;
    }
    __syncthreads();
  }

  float* t0 = scratch;
  float* t1 = scratch + 1024;
  float* t2 = scratch + 2048;
  int r0 = blockIdx.x*16;

  for (int rr = y; rr < 16; rr += 8)
    t0[rr*64 + c] = lrelu_f(z[(r0 + rr)*64 + c]*scl[c] + sft[c]);
  __syncthreads();
  {
    float a0 = l1b[c], a1 = a0;
    for (int k = 0; k < 64; ++k) {
      float w = W1s[k*64 + c];
      a0 = fmaf(t0[y*64 + k],       w, a0);
      a1 = fmaf(t0[(y + 8)*64 + k], w, a1);
    }
    t1[y*64 + c]       = lrelu_f(a0);
    t1[(y + 8)*64 + c] = lrelu_f(a1);
  }
  __syncthreads();
  if (c < 32) {
    float v0 = l2b[c], v1 = v0;
    for (int k = 0; k < 64; ++k) {
      float w = W2s[k*32 + c];
      v0 = fmaf(t1[y*64 + k],       w, v0);
      v1 = fmaf(t1[(y + 8)*64 + k], w, v1);
    }
    t2[y*32 + c]       = lrelu_f(v0) + nf[(r0 + y)*32 + c];
    t2[(y + 8)*32 + c] = lrelu_f(v1) + nf[(r0 + y + 8)*32 + c];
  }
  __syncthreads();
  {
    float av0 = epb1[c], av1 = av0;
    float bv0 = 0.f, bv1 = 0.f;
    for (int k = 0; k < 32; ++k) {
      float wa = Was[k*64 + c], wb = Wbs[k*64 + c];
      av0 = fmaf(t2[y*32 + k], wa, av0);       bv0 = fmaf(t2[y*32 + k], wb, bv0);
      av1 = fmaf(t2[(y + 8)*32 + k], wa, av1); bv1 = fmaf(t2[(y + 8)*32 + k], wb, bv1);
    }
    Ah[(r0 + y)*64 + c]     = (_Float16)av0;  Bh[(r0 + y)*64 + c]     = (_Float16)bv0;
    Ah[(r0 + y + 8)*64 + c] = (_Float16)av1;  Bh[(r0 + y + 8)*64 + c] = (_Float16)bv1;
  }
}

// ---------------------------------------------------------------------------
// Edge MLP. Weights staged in LDS (16KB/block, shared by 4 waves) — frees the
// 64 persistent weight VGPRs so actual allocation lands <=128 regs -> 4
// waves/SIMD residency (rounds 4-10 were pinned at 2-3; latency hiding is the
// binding constraint: MfmaUtil 17% with both pipes idle).
__global__ __launch_bounds__(256, 4) void k_edges_f16(
    const _Float16* __restrict__ Ah, const _Float16* __restrict__ Bh,
    const _Float16* __restrict__ Wf,
    const float* __restrict__ b2, const float* __restrict__ b3,
    const float* __restrict__ w4, const float* __restrict__ b4,
    float* __restrict__ out) {
  __shared__ _Float16 Wl[8192];   // [2][4096] fragment-ordered, 16KB
  int tid = threadIdx.x, wid = tid >> 6, lane = tid & 63;
  int c = lane & 15, g = lane >> 4;

  {
    const float4* src = (const float4*)Wf;
    float4* dst = (float4*)Wl;
    for (int i = tid; i < 1024; i += 256) dst[i] = src[i];
  }

  // wave -> (s, chunk) band decode (uniform per wave)
  int w = blockIdx.x*4 + wid;
  int cum, kk, sbase;
  if (w < 1524) { cum = 0; kk = 12; sbase = 0; }
  else {
    cum = 1524; kk = 11; sbase = 127;
    while (kk > 1 && w >= cum + 128*kk) { cum += 128*kk; sbase += 128; --kk; }
  }
  int idx = w - cum;
  int q = idx / kk;
  int s = sbase + q;
  int t0 = s + 1 + ((idx - q*kk) << 7);

  // biases / w4 resident (40 regs)
  f32x4 b2v[4], b3v[4];
  v2hf w4h[8];
  int g4 = g*4;
#pragma unroll
  for (int m = 0; m < 4; ++m) {
#pragma unroll
    for (int r = 0; r < 4; ++r) {
      int f = 16*m + g4 + r;
      b2v[m][r] = b2[f]; b3v[m][r] = b3[f];
    }
    v2hf wa = { (__fp16)w4[16*m + g4],     (__fp16)w4[16*m + g4 + 1] };
    v2hf wb = { (__fp16)w4[16*m + g4 + 2], (__fp16)w4[16*m + g4 + 3] };
    w4h[2*m] = wa; w4h[2*m + 1] = wb;
  }
  float b4v = b4[0];

  V8H zu; zu.f4 = make_float4(0.f, 0.f, 0.f, 0.f);
  const v8h vzero = zu.v;
  const v2hf z2 = { (__fp16)0.f, (__fp16)0.f };

  // A[s] fragments: loop-invariant
  V8H a0, a1;
  a0.f4 = *(const float4*)(Ah + s*64 + g*8);
  a1.f4 = *(const float4*)(Ah + s*64 + 32 + g*8);

  // first B prefetch (no clamp: overread lands in Wf region of ws)
  int tl = t0 + c;
  V8H y0, y1;
  y0.f4 = *(const float4*)(Bh + tl*64 + g*8);
  y1.f4 = *(const float4*)(Bh + tl*64 + 32 + g*8);

  const v8h* wl = (const v8h*)Wl;
  __syncthreads();                       // Wl ready

  for (int it = 0; it < 8; ++it) {
    int tb = t0 + (it << 4);
    if (tb >= NN) break;                 // uniform
    int t = tb + c;

    V8H f0, f1;
    f0.v = __builtin_elementwise_max(a0.v + y0.v, vzero);
    f1.v = __builtin_elementwise_max(a1.v + y1.v, vzero);

    // prefetch next group's B rows
    int tn = tb + 16 + c;
    y0.f4 = *(const float4*)(Bh + tn*64 + g*8);
    y1.f4 = *(const float4*)(Bh + tn*64 + 32 + g*8);

    // layer 2 (weight frags from LDS, bias as C-operand)
    __builtin_amdgcn_s_setprio(1);
    f32x4 acc[4];
#pragma unroll
    for (int m = 0; m < 4; ++m)
      acc[m] = __builtin_amdgcn_mfma_f32_16x16x32_f16(wl[m*64 + lane], f0.v, b2v[m], 0, 0, 0);
#pragma unroll
    for (int m = 0; m < 4; ++m)
      acc[m] = __builtin_amdgcn_mfma_f32_16x16x32_f16(wl[(4 + m)*64 + lane], f1.v, acc[m], 0, 0, 0);
    __builtin_amdgcn_s_setprio(0);

    // relu via packed f16 max after cvt_pkrtz
    V8H p0, p1;
#pragma unroll
    for (int m = 0; m < 2; ++m) {
      p0.h2[2*m]     = __builtin_elementwise_max(__builtin_amdgcn_cvt_pkrtz(acc[m][0],   acc[m][1]),   z2);
      p0.h2[2*m + 1] = __builtin_elementwise_max(__builtin_amdgcn_cvt_pkrtz(acc[m][2],   acc[m][3]),   z2);
      p1.h2[2*m]     = __builtin_elementwise_max(__builtin_amdgcn_cvt_pkrtz(acc[m+2][0], acc[m+2][1]), z2);
      p1.h2[2*m + 1] = __builtin_elementwise_max(__builtin_amdgcn_cvt_pkrtz(acc[m+2][2], acc[m+2][3]), z2);
    }

    // layer 3
    __builtin_amdgcn_s_setprio(1);
    f32x4 acc3[4];
#pragma unroll
    for (int m = 0; m < 4; ++m)
      acc3[m] = __builtin_amdgcn_mfma_f32_16x16x32_f16(wl[512 + m*64 + lane], p0.v, b3v[m], 0, 0, 0);
#pragma unroll
    for (int m = 0; m < 4; ++m)
      acc3[m] = __builtin_amdgcn_mfma_f32_16x16x32_f16(wl[512 + (4 + m)*64 + lane], p1.v, acc3[m], 0, 0, 0);
    __builtin_amdgcn_s_setprio(0);

    // layer 4: relu -> f16 pack -> v_dot2 with packed w4
    float p = 0.f;
#pragma unroll
    for (int m = 0; m < 4; ++m) {
      v2hf l0 = __builtin_elementwise_max(
          __builtin_amdgcn_cvt_pkrtz(acc3[m][0], acc3[m][1]), z2);
      v2hf l1 = __builtin_elementwise_max(
          __builtin_amdgcn_cvt_pkrtz(acc3[m][2], acc3[m][3]), z2);
      p = __builtin_amdgcn_fdot2(l0, w4h[2*m],     p, false);
      p = __builtin_amdgcn_fdot2(l1, w4h[2*m + 1], p, false);
    }
    p += __shfl_xor(p, 16, 64);
    p += __shfl_xor(p, 32, 64);
    float ez = __builtin_amdgcn_exp2f(-1.44269504f * (p + b4v));
    float prob = __builtin_amdgcn_rcpf(1.f + ez);
    if (lane < 16 && t < NN) out[s*NN + t] = prob;   // upper triangle, coalesced
  }
}

// mirror: lower = upper^T, diag = 0. Triangular grid.
__global__ __launch_bounds__(256) void k_mirror(float* __restrict__ out) {
  __shared__ float tile[32][33];
  int k = blockIdx.x;
  int bi = (int)((sqrtf(8.f*k + 1.f) - 1.f)*0.5f);
  while (bi*(bi + 1)/2 > k) --bi;
  while ((bi + 1)*(bi + 2)/2 <= k) ++bi;
  int bj = k - bi*(bi + 1)/2;
  int i0 = bi*32, j0 = bj*32;
  int tx = threadIdx.x & 31, ty = threadIdx.x >> 5;
#pragma unroll
  for (int r = 0; r < 4; ++r)
    tile[ty + r*8][tx] = out[(j0 + ty + r*8)*NN + i0 + tx];
  __syncthreads();
#pragma unroll
  for (int r = 0; r < 4; ++r) {
    int row = ty + r*8;
    int i = i0 + row, j = j0 + tx;
    if (bi > bj)      out[i*NN + j] = tile[tx][row];
    else if (i > j)   out[i*NN + j] = tile[tx][row];
    else if (i == j)  out[i*NN + j] = 0.f;
  }
}

// ---------------------------------------------------------------------------
extern "C" void kernel_launch(void* const* d_in, const int* in_sizes, int n_in,
                              void* d_out, int out_size, void* d_ws, size_t ws_size,
                              hipStream_t stream) {
  const float* nf     = (const float*)d_in[1];
  const float* c1_eps = (const float*)d_in[2];
  const float* c1_w1  = (const float*)d_in[3];
  const float* c1_b1  = (const float*)d_in[4];
  const float* c1_w2  = (const float*)d_in[5];
  const float* c1_b2  = (const float*)d_in[6];
  const float* c1_g   = (const float*)d_in[7];
  const float* c1_be  = (const float*)d_in[8];
  const float* cv_eps = (const float*)d_in[9];
  const float* cv_w1  = (const float*)d_in[10];
  const float* cv_b1  = (const float*)d_in[11];
  const float* cv_w2  = (const float*)d_in[12];
  const float* cv_b2  = (const float*)d_in[13];
  const float* cv_g   = (const float*)d_in[14];
  const float* cv_be  = (const float*)d_in[15];
  const float* lin1_w = (const float*)d_in[16];
  const float* lin1_b = (const float*)d_in[17];
  const float* lin2_w = (const float*)d_in[18];
  const float* lin2_b = (const float*)d_in[19];
  const float* ep_w1  = (const float*)d_in[20];
  const float* ep_b1  = (const float*)d_in[21];
  const float* ep_w2  = (const float*)d_in[22];
  const float* ep_b2  = (const float*)d_in[23];
  const float* ep_w3  = (const float*)d_in[24];
  const float* ep_b3  = (const float*)d_in[25];
  const float* ep_w4  = (const float*)d_in[26];
  const float* ep_b4  = (const float*)d_in[27];

  float* ws = (float*)d_ws;
  float* zA    = ws;
  float* zB    = zA + NN*64;
  _Float16* Ah = (_Float16*)(zB + NN*64);
  _Float16* Bh = Ah + NN*64;
  _Float16* Wf = Bh + NN*64;   // absorbs Bh prefetch overread (<4KB, Wf=16KB)

  float* out = (float*)d_out;

  k_gin<32, true><<<112, 512, 0, stream>>>(nf, nullptr, nullptr, c1_eps,
      c1_w1, c1_b1, c1_w2, c1_b2, zA, ep_w2, ep_w3, Wf);

  k_gin<64, false><<<96, 512, 0, stream>>>(zA, c1_g, c1_be, cv_eps,
      cv_w1, cv_b1, cv_w2, cv_b2, zB, nullptr, nullptr, nullptr);

  k_gin<64, false><<<96, 512, 0, stream>>>(zB, cv_g, cv_be, cv_eps + 1,
      cv_w1 + HH*HH, cv_b1 + HH, cv_w2 + HH*HH, cv_b2 + HH, zA,
      nullptr, nullptr, nullptr);

  k_head<<<96, 512, 0, stream>>>(zA, cv_g + HH, cv_be + HH,
                                 lin1_w, lin1_b, lin2_w, lin2_b, nf,
                                 ep_w1, ep_b1, Ah, Bh);

  k_edges_f16<<<EBLK, 256, 0, stream>>>(Ah, Bh, Wf, ep_b2, ep_b3, ep_w4, ep_b4, out);

  k_mirror<<<1176, 256, 0, stream>>>(out);
}

// Round 12
// 81.202 us; speedup vs baseline: 3.9330x; 1.0719x over previous
//
#include <hip/hip_runtime.h>
#include <math.h>

#define NN 1536
#define FF 32
#define HH 64
#define EE (NN*(NN-1)/2)
#define EBLK 2493          // 2493 blocks * 4 waves = 9972 = exact padded chunk count
#define BN_EPS 1e-5f
#define SLOPE 0.01f

typedef _Float16 v8h  __attribute__((ext_vector_type(8)));
typedef __fp16   v2hf __attribute__((ext_vector_type(2)));
typedef float    f32x4 __attribute__((ext_vector_type(4)));

union V8H { v8h v; v2hf h2[4]; float4 f4; };

__device__ __forceinline__ float lrelu_f(float v){ return v >= 0.f ? v : SLOPE*v; }

// ---------------------------------------------------------------------------
// Node pipeline, restructured: NO per-block full-z sweeps. Cross-block data
// (BN stats, prefix bases) flows through tiny per-chunk partial arrays with
// kernel-boundary ordering (free, coherent) instead of either (a) redundant
// 590KB/block sweeps (r6-r11) or (b) intra-kernel fences (r5 disaster).
//   k_first : chunk-sums of nf -> H   (+ edge-weight prep in blocks 96..127)
//   k_mmp   : prefix from H (24KB) -> u-scan -> relu(relu(u@W1+b1)@W2+b2)
//             -> zout, AND emits next layer's raw partials P from registers
//   k_bn    : stats from P (48KB) -> h=lrelu(BN(z)) -> hbuf + chunk-sums H
//   k_head2 : stats from P -> head MLP -> Ah/Bh (f16)

__global__ __launch_bounds__(256) void k_first(
    const float* __restrict__ nf, float* __restrict__ H,
    const float* __restrict__ pw2, const float* __restrict__ pw3,
    _Float16* __restrict__ pwf) {
  int bid = blockIdx.x, tid = threadIdx.x;
  if (bid >= 96) {
    int i = (bid - 96)*256 + tid;     // 8192 over 32 blocks
    if (i < 8192) {
      int mat = i >> 12, r = i & 4095;
      int k = r >> 6, cout = r & 63;
      int m = cout >> 4, cc = cout & 15;
      int q, g, b;
      if (mat == 0) { q = k >> 5; g = (k >> 3) & 3; b = k & 7; }
      else { int mF = k >> 4; g = (k >> 2) & 3; int rr = k & 3; q = mF >> 1; b = ((mF & 1) << 2) | rr; }
      const float* W = mat ? pw3 : pw2;
      pwf[mat*4096 + ((q*4 + m)*64 + (g*16 + cc))*8 + b] = (_Float16)W[r];
    }
    return;
  }
  __shared__ float part[8][32];
  int c = tid & 31, y = tid >> 5;     // 8 row-groups, 2 rows each
  float s = nf[(bid*16 + y)*32 + c] + nf[(bid*16 + y + 8)*32 + c];
  part[y][c] = s;
  __syncthreads();
  if (y == 0) {
    float S = 0.f;
#pragma unroll
    for (int r = 0; r < 8; ++r) S += part[r][c];
    H[bid*64 + c] = S;
  }
}

// stats from P; h = lrelu(BN(z)); write hbuf + chunk-sums H
__global__ __launch_bounds__(256) void k_bn(
    const float* __restrict__ z, const float* __restrict__ P,
    const float* __restrict__ gg, const float* __restrict__ be,
    float* __restrict__ hbuf, float* __restrict__ H) {
  __shared__ float sums[2][128];
  __shared__ float scl[64], sft[64];
  __shared__ float part[4][64];
  int tid = threadIdx.x, bid = blockIdx.x;
  {
    int c2 = tid & 127, half = tid >> 7;
    float S0 = 0.f, S1 = 0.f;
    int j0 = half*48;
    for (int j = j0; j < j0 + 48; j += 2) { S0 += P[j*128 + c2]; S1 += P[(j+1)*128 + c2]; }
    sums[half][c2] = S0 + S1;
  }
  __syncthreads();
  if (tid < 64) {
    float S = sums[0][tid] + sums[1][tid];
    float Q = sums[0][64 + tid] + sums[1][64 + tid];
    float m  = S * (1.f/NN);
    float iv = rsqrtf(Q * (1.f/NN) - m*m + BN_EPS);
    float sc = iv * gg[tid];
    scl[tid] = sc;
    sft[tid] = be[tid] - m*sc;
  }
  __syncthreads();
  int c = tid & 63, y = tid >> 6;     // 4 rows each: y,y+4,y+8,y+12
  float sc = scl[c], sh = sft[c];
  float hs = 0.f;
#pragma unroll
  for (int i = 0; i < 4; ++i) {
    int rr = y + 4*i;
    float h = lrelu_f(z[(bid*16 + rr)*64 + c]*sc + sh);
    hbuf[(bid*16 + rr)*64 + c] = h;
    hs += h;
  }
  part[y][c] = hs;
  __syncthreads();
  if (y == 0)
    H[bid*64 + c] = part[0][c] + part[1][c] + part[2][c] + part[3][c];
}

// prefix from H -> scan -> double matmul -> zout + next-layer partials P
template<int DIN>
__global__ __launch_bounds__(512) void k_mmp(
    const float* __restrict__ hb, const float* __restrict__ H,
    const float* __restrict__ eps_p,
    const float* __restrict__ W1, const float* __restrict__ b1,
    const float* __restrict__ W2, const float* __restrict__ b2,
    float* __restrict__ zout, float* __restrict__ P) {
  __shared__ float W1s[DIN*64];
  __shared__ float W2s[4096];
  __shared__ float red[8][64];
  __shared__ float pf[64];
  __shared__ float hh[16][DIN];
  __shared__ float uls[16*DIN];
  __shared__ float t1s[16][64];
  __shared__ float pp[8][64], pq[8][64];
  int tid = threadIdx.x, bid = blockIdx.x;
  int c = tid & 63, y = tid >> 6;     // 8 row-groups
  for (int i = tid; i < DIN*64; i += 512) W1s[i] = W1[i];
  for (int i = tid; i < 4096; i += 512)   W2s[i] = W2[i];

  // prefix partials over chunk-sums (j < bid) + h tile load
  {
    float s = 0.f;
    if (c < DIN) for (int j = y; j < bid; j += 8) s += H[j*64 + c];
    red[y][c] = s;
  }
  if (c < DIN) {
    hh[y][c]     = hb[(bid*16 + y)*DIN + c];
    hh[y + 8][c] = hb[(bid*16 + y + 8)*DIN + c];
  }
  __syncthreads();
  if (y == 0 && c < DIN) {
    float S = 0.f;
#pragma unroll
    for (int r = 0; r < 8; ++r) S += red[r][c];
    pf[c] = S;
  }
  __syncthreads();

  float e1 = 1.f + eps_p[0];
  if (c < DIN) {
    for (int rr = y; rr < 16; rr += 8) {
      float run = pf[c];
      for (int r2 = 0; r2 < rr; ++r2) run += hh[r2][c];
      uls[rr*DIN + c] = e1*hh[rr][c] + run;
    }
  }
  __syncthreads();

  float a0 = b1[c], a1 = a0;
  for (int k = 0; k < DIN; ++k) {
    float w = W1s[k*64 + c];
    a0 = fmaf(uls[y*DIN + k],       w, a0);
    a1 = fmaf(uls[(y + 8)*DIN + k], w, a1);
  }
  t1s[y][c]     = fmaxf(a0, 0.f);
  t1s[y + 8][c] = fmaxf(a1, 0.f);
  __syncthreads();

  float z0 = b2[c], z1 = z0;
  for (int k = 0; k < 64; ++k) {
    float w = W2s[k*64 + c];
    z0 = fmaf(t1s[y][k],     w, z0);
    z1 = fmaf(t1s[y + 8][k], w, z1);
  }
  z0 = fmaxf(z0, 0.f); z1 = fmaxf(z1, 0.f);
  zout[(bid*16 + y)*64 + c]     = z0;
  zout[(bid*16 + y + 8)*64 + c] = z1;

  pp[y][c] = z0 + z1;
  pq[y][c] = z0*z0 + z1*z1;
  __syncthreads();
  if (y == 0) {
    float S = 0.f, Q = 0.f;
#pragma unroll
    for (int r = 0; r < 8; ++r) { S += pp[r][c]; Q += pq[r][c]; }
    P[bid*128 + c]      = S;
    P[bid*128 + 64 + c] = Q;
  }
}

// head: stats from P; h3=lrelu(BN(z)); hf=lrelu(lrelu(h3@lin1)@lin2)+nf;
// A=hf@W1a+b1e; B=hf@W1b (f16)
__global__ __launch_bounds__(512) void k_head2(
    const float* __restrict__ z, const float* __restrict__ P,
    const float* __restrict__ gg, const float* __restrict__ be,
    const float* __restrict__ l1w, const float* __restrict__ l1b,
    const float* __restrict__ l2w, const float* __restrict__ l2b,
    const float* __restrict__ nf,
    const float* __restrict__ epw1, const float* __restrict__ epb1,
    _Float16* __restrict__ Ah, _Float16* __restrict__ Bh) {
  __shared__ float W1s[4096];
  __shared__ float W2s[2048];
  __shared__ float Was[2048];
  __shared__ float Wbs[2048];
  __shared__ float sums[4][128];
  __shared__ float scratch[4096];
  __shared__ float scl[64], sft[64];
  int tid = threadIdx.x, c = tid & 63, y = tid >> 6;
  for (int i = tid; i < 4096; i += 512) W1s[i] = l1w[i];
  for (int i = tid; i < 2048; i += 512) { W2s[i] = l2w[i]; Was[i] = epw1[i]; Wbs[i] = epw1[2048 + i]; }

  {
    int c2 = tid & 127, q = tid >> 7;   // 4 quarters x 24 chunks
    float S = 0.f;
    for (int j = q*24; j < q*24 + 24; ++j) S += P[j*128 + c2];
    sums[q][c2] = S;
  }
  __syncthreads();
  if (tid < 64) {
    float S = sums[0][tid] + sums[1][tid] + sums[2][tid] + sums[3][tid];
    float Q = sums[0][64+tid] + sums[1][64+tid] + sums[2][64+tid] + sums[3][64+tid];
    float m  = S * (1.f/NN);
    float iv = rsqrtf(Q * (1.f/NN) - m*m + BN_EPS);
    float sc = iv * gg[tid];
    scl[tid] = sc;
    sft[tid] = be[tid] - m*sc;
  }
  __syncthreads();

  float* t0 = scratch;
  float* t1 = scratch + 1024;
  float* t2 = scratch + 2048;
  int r0 = blockIdx.x*16;

  for (int rr = y; rr < 16; rr += 8)
    t0[rr*64 + c] = lrelu_f(z[(r0 + rr)*64 + c]*scl[c] + sft[c]);
  __syncthreads();
  {
    float a0 = l1b[c], a1 = a0;
    for (int k = 0; k < 64; ++k) {
      float w = W1s[k*64 + c];
      a0 = fmaf(t0[y*64 + k],       w, a0);
      a1 = fmaf(t0[(y + 8)*64 + k], w, a1);
    }
    t1[y*64 + c]       = lrelu_f(a0);
    t1[(y + 8)*64 + c] = lrelu_f(a1);
  }
  __syncthreads();
  if (c < 32) {
    float v0 = l2b[c], v1 = v0;
    for (int k = 0; k < 64; ++k) {
      float w = W2s[k*32 + c];
      v0 = fmaf(t1[y*64 + k],       w, v0);
      v1 = fmaf(t1[(y + 8)*64 + k], w, v1);
    }
    t2[y*32 + c]       = lrelu_f(v0) + nf[(r0 + y)*32 + c];
    t2[(y + 8)*32 + c] = lrelu_f(v1) + nf[(r0 + y + 8)*32 + c];
  }
  __syncthreads();
  {
    float av0 = epb1[c], av1 = av0;
    float bv0 = 0.f, bv1 = 0.f;
    for (int k = 0; k < 32; ++k) {
      float wa = Was[k*64 + c], wb = Wbs[k*64 + c];
      av0 = fmaf(t2[y*32 + k], wa, av0);       bv0 = fmaf(t2[y*32 + k], wb, bv0);
      av1 = fmaf(t2[(y + 8)*32 + k], wa, av1); bv1 = fmaf(t2[(y + 8)*32 + k], wb, bv1);
    }
    Ah[(r0 + y)*64 + c]     = (_Float16)av0;  Bh[(r0 + y)*64 + c]     = (_Float16)bv0;
    Ah[(r0 + y + 8)*64 + c] = (_Float16)av1;  Bh[(r0 + y + 8)*64 + c] = (_Float16)bv1;
  }
}

// ---------------------------------------------------------------------------
// Edge MLP (unchanged from r11: LDS-staged weights, row-tiled, 4 waves/EU).
__global__ __launch_bounds__(256, 4) void k_edges_f16(
    const _Float16* __restrict__ Ah, const _Float16* __restrict__ Bh,
    const _Float16* __restrict__ Wf,
    const float* __restrict__ b2, const float* __restrict__ b3,
    const float* __restrict__ w4, const float* __restrict__ b4,
    float* __restrict__ out) {
  __shared__ _Float16 Wl[8192];
  int tid = threadIdx.x, wid = tid >> 6, lane = tid & 63;
  int c = lane & 15, g = lane >> 4;

  {
    const float4* src = (const float4*)Wf;
    float4* dst = (float4*)Wl;
    for (int i = tid; i < 1024; i += 256) dst[i] = src[i];
  }

  int w = blockIdx.x*4 + wid;
  int cum, kk, sbase;
  if (w < 1524) { cum = 0; kk = 12; sbase = 0; }
  else {
    cum = 1524; kk = 11; sbase = 127;
    while (kk > 1 && w >= cum + 128*kk) { cum += 128*kk; sbase += 128; --kk; }
  }
  int idx = w - cum;
  int q = idx / kk;
  int s = sbase + q;
  int t0 = s + 1 + ((idx - q*kk) << 7);

  f32x4 b2v[4], b3v[4];
  v2hf w4h[8];
  int g4 = g*4;
#pragma unroll
  for (int m = 0; m < 4; ++m) {
#pragma unroll
    for (int r = 0; r < 4; ++r) {
      int f = 16*m + g4 + r;
      b2v[m][r] = b2[f]; b3v[m][r] = b3[f];
    }
    v2hf wa = { (__fp16)w4[16*m + g4],     (__fp16)w4[16*m + g4 + 1] };
    v2hf wb = { (__fp16)w4[16*m + g4 + 2], (__fp16)w4[16*m + g4 + 3] };
    w4h[2*m] = wa; w4h[2*m + 1] = wb;
  }
  float b4v = b4[0];

  V8H zu; zu.f4 = make_float4(0.f, 0.f, 0.f, 0.f);
  const v8h vzero = zu.v;
  const v2hf z2 = { (__fp16)0.f, (__fp16)0.f };

  V8H a0, a1;
  a0.f4 = *(const float4*)(Ah + s*64 + g*8);
  a1.f4 = *(const float4*)(Ah + s*64 + 32 + g*8);

  int tl = t0 + c;
  V8H y0, y1;
  y0.f4 = *(const float4*)(Bh + tl*64 + g*8);
  y1.f4 = *(const float4*)(Bh + tl*64 + 32 + g*8);

  const v8h* wl = (const v8h*)Wl;
  __syncthreads();

  for (int it = 0; it < 8; ++it) {
    int tb = t0 + (it << 4);
    if (tb >= NN) break;
    int t = tb + c;

    V8H f0, f1;
    f0.v = __builtin_elementwise_max(a0.v + y0.v, vzero);
    f1.v = __builtin_elementwise_max(a1.v + y1.v, vzero);

    int tn = tb + 16 + c;
    y0.f4 = *(const float4*)(Bh + tn*64 + g*8);
    y1.f4 = *(const float4*)(Bh + tn*64 + 32 + g*8);

    __builtin_amdgcn_s_setprio(1);
    f32x4 acc[4];
#pragma unroll
    for (int m = 0; m < 4; ++m)
      acc[m] = __builtin_amdgcn_mfma_f32_16x16x32_f16(wl[m*64 + lane], f0.v, b2v[m], 0, 0, 0);
#pragma unroll
    for (int m = 0; m < 4; ++m)
      acc[m] = __builtin_amdgcn_mfma_f32_16x16x32_f16(wl[(4 + m)*64 + lane], f1.v, acc[m], 0, 0, 0);
    __builtin_amdgcn_s_setprio(0);

    V8H p0, p1;
#pragma unroll
    for (int m = 0; m < 2; ++m) {
      p0.h2[2*m]     = __builtin_elementwise_max(__builtin_amdgcn_cvt_pkrtz(acc[m][0],   acc[m][1]),   z2);
      p0.h2[2*m + 1] = __builtin_elementwise_max(__builtin_amdgcn_cvt_pkrtz(acc[m][2],   acc[m][3]),   z2);
      p1.h2[2*m]     = __builtin_elementwise_max(__builtin_amdgcn_cvt_pkrtz(acc[m+2][0], acc[m+2][1]), z2);
      p1.h2[2*m + 1] = __builtin_elementwise_max(__builtin_amdgcn_cvt_pkrtz(acc[m+2][2], acc[m+2][3]), z2);
    }

    __builtin_amdgcn_s_setprio(1);
    f32x4 acc3[4];
#pragma unroll
    for (int m = 0; m < 4; ++m)
      acc3[m] = __builtin_amdgcn_mfma_f32_16x16x32_f16(wl[512 + m*64 + lane], p0.v, b3v[m], 0, 0, 0);
#pragma unroll
    for (int m = 0; m < 4; ++m)
      acc3[m] = __builtin_amdgcn_mfma_f32_16x16x32_f16(wl[512 + (4 + m)*64 + lane], p1.v, acc3[m], 0, 0, 0);
    __builtin_amdgcn_s_setprio(0);

    float p = 0.f;
#pragma unroll
    for (int m = 0; m < 4; ++m) {
      v2hf l0 = __builtin_elementwise_max(
          __builtin_amdgcn_cvt_pkrtz(acc3[m][0], acc3[m][1]), z2);
      v2hf l1 = __builtin_elementwise_max(
          __builtin_amdgcn_cvt_pkrtz(acc3[m][2], acc3[m][3]), z2);
      p = __builtin_amdgcn_fdot2(l0, w4h[2*m],     p, false);
      p = __builtin_amdgcn_fdot2(l1, w4h[2*m + 1], p, false);
    }
    p += __shfl_xor(p, 16, 64);
    p += __shfl_xor(p, 32, 64);
    float ez = __builtin_amdgcn_exp2f(-1.44269504f * (p + b4v));
    float prob = __builtin_amdgcn_rcpf(1.f + ez);
    if (lane < 16 && t < NN) out[s*NN + t] = prob;
  }
}

// mirror: lower = upper^T, diag = 0. Triangular grid.
__global__ __launch_bounds__(256) void k_mirror(float* __restrict__ out) {
  __shared__ float tile[32][33];
  int k = blockIdx.x;
  int bi = (int)((sqrtf(8.f*k + 1.f) - 1.f)*0.5f);
  while (bi*(bi + 1)/2 > k) --bi;
  while ((bi + 1)*(bi + 2)/2 <= k) ++bi;
  int bj = k - bi*(bi + 1)/2;
  int i0 = bi*32, j0 = bj*32;
  int tx = threadIdx.x & 31, ty = threadIdx.x >> 5;
#pragma unroll
  for (int r = 0; r < 4; ++r)
    tile[ty + r*8][tx] = out[(j0 + ty + r*8)*NN + i0 + tx];
  __syncthreads();
#pragma unroll
  for (int r = 0; r < 4; ++r) {
    int row = ty + r*8;
    int i = i0 + row, j = j0 + tx;
    if (bi > bj)      out[i*NN + j] = tile[tx][row];
    else if (i > j)   out[i*NN + j] = tile[tx][row];
    else if (i == j)  out[i*NN + j] = 0.f;
  }
}

// ---------------------------------------------------------------------------
extern "C" void kernel_launch(void* const* d_in, const int* in_sizes, int n_in,
                              void* d_out, int out_size, void* d_ws, size_t ws_size,
                              hipStream_t stream) {
  const float* nf     = (const float*)d_in[1];
  const float* c1_eps = (const float*)d_in[2];
  const float* c1_w1  = (const float*)d_in[3];
  const float* c1_b1  = (const float*)d_in[4];
  const float* c1_w2  = (const float*)d_in[5];
  const float* c1_b2  = (const float*)d_in[6];
  const float* c1_g   = (const float*)d_in[7];
  const float* c1_be  = (const float*)d_in[8];
  const float* cv_eps = (const float*)d_in[9];
  const float* cv_w1  = (const float*)d_in[10];
  const float* cv_b1  = (const float*)d_in[11];
  const float* cv_w2  = (const float*)d_in[12];
  const float* cv_b2  = (const float*)d_in[13];
  const float* cv_g   = (const float*)d_in[14];
  const float* cv_be  = (const float*)d_in[15];
  const float* lin1_w = (const float*)d_in[16];
  const float* lin1_b = (const float*)d_in[17];
  const float* lin2_w = (const float*)d_in[18];
  const float* lin2_b = (const float*)d_in[19];
  const float* ep_w1  = (const float*)d_in[20];
  const float* ep_b1  = (const float*)d_in[21];
  const float* ep_w2  = (const float*)d_in[22];
  const float* ep_b2  = (const float*)d_in[23];
  const float* ep_w3  = (const float*)d_in[24];
  const float* ep_b3  = (const float*)d_in[25];
  const float* ep_w4  = (const float*)d_in[26];
  const float* ep_b4  = (const float*)d_in[27];

  float* ws = (float*)d_ws;
  float* zA    = ws;                       // [NN*64]
  float* zB    = zA + NN*64;               // [NN*64]
  float* hbuf  = zB + NN*64;               // [NN*64]
  float* H     = hbuf + NN*64;             // [96*64]
  float* P     = H + 96*64;                // [96*128]
  _Float16* Ah = (_Float16*)(P + 96*128);  // [NN*64] f16
  _Float16* Bh = Ah + NN*64;               // [NN*64] f16
  _Float16* Wf = Bh + NN*64;               // [2*4096] f16 (absorbs Bh overread)

  float* out = (float*)d_out;

  // layer 1: chunk-sums of nf (+ weight prep), then scan+matmuls -> zA, P
  k_first<<<128, 256, 0, stream>>>(nf, H, ep_w2, ep_w3, Wf);
  k_mmp<32><<<96, 512, 0, stream>>>(nf, H, c1_eps, c1_w1, c1_b1, c1_w2, c1_b2, zA, P);

  // layer 2
  k_bn<<<96, 256, 0, stream>>>(zA, P, c1_g, c1_be, hbuf, H);
  k_mmp<64><<<96, 512, 0, stream>>>(hbuf, H, cv_eps, cv_w1, cv_b1, cv_w2, cv_b2, zB, P);

  // layer 3
  k_bn<<<96, 256, 0, stream>>>(zB, P, cv_g, cv_be, hbuf, H);
  k_mmp<64><<<96, 512, 0, stream>>>(hbuf, H, cv_eps + 1,
      cv_w1 + HH*HH, cv_b1 + HH, cv_w2 + HH*HH, cv_b2 + HH, zA, P);

  // head (stats from P)
  k_head2<<<96, 512, 0, stream>>>(zA, P, cv_g + HH, cv_be + HH,
                                  lin1_w, lin1_b, lin2_w, lin2_b, nf,
                                  ep_w1, ep_b1, Ah, Bh);

  // edges + mirror
  k_edges_f16<<<EBLK, 256, 0, stream>>>(Ah, Bh, Wf, ep_b2, ep_b3, ep_w4, ep_b4, out);
  k_mirror<<<1176, 256, 0, stream>>>(out);
}